// Round 4
// baseline (267.520 us; speedup 1.0000x reference)
//
#include <hip/hip_runtime.h>
#include <hip/hip_bf16.h>

typedef short short8 __attribute__((ext_vector_type(8)));
typedef short short4v __attribute__((ext_vector_type(4)));
typedef float f32x4 __attribute__((ext_vector_type(4)));

constexpr int BB = 8192;   // batch
constexpr int LL = 50;     // seq len
constexpr int DE = 128;    // emb dim
constexpr int DD = 392;    // total input dim
constexpr int HH1 = 256;
constexpr int HH2 = 128;

__device__ __forceinline__ short f2b(float x) {
    __hip_bfloat16 h = __float2bfloat16(x);   // RNE
    return __builtin_bit_cast(short, h);
}
__device__ __forceinline__ float b2f(short v) {
    unsigned u = ((unsigned)(unsigned short)v) << 16;
    return __builtin_bit_cast(float, u);
}

// ---------------------------------------------------------------------------
// prep: Wq' = W1q + W1(q-k)  (bf16, [128][64])
// ---------------------------------------------------------------------------
__global__ __launch_bounds__(256) void prep_wqp(const float* __restrict__ w1,
                                                short* __restrict__ Wqpb) {
    int idx = blockIdx.x * 256 + threadIdx.x;       // d*64+h, 8192
    Wqpb[idx] = f2b(w1[idx] + w1[idx + 16384]);
}

// ---------------------------------------------------------------------------
// prep: Wk' = W1k - W1d and Wp, bf16 in MFMA B-fragment order:
// o = [kt(4)][nt(4)][lane(64)][e(8)]; element = W[k][h],
// k = kt*32 + (lane>>4)*8 + e, h = nt*16 + (lane&15)
// ---------------------------------------------------------------------------
__global__ __launch_bounds__(256) void prep_wkwp(const float* __restrict__ w1,
                                                 short* __restrict__ WkFb,
                                                 short* __restrict__ WpFb) {
    int o = blockIdx.x * 256 + threadIdx.x;         // 8192
    int e = o & 7, lane = (o >> 3) & 63, nt = (o >> 9) & 3, kt = o >> 11;
    int k = (kt << 5) + ((lane >> 4) << 3) + e;
    int h = (nt << 4) + (lane & 15);
    WkFb[o] = f2b(w1[(128 + k) * 64 + h] - w1[(256 + k) * 64 + h]);
    WpFb[o] = f2b(w1[(384 + k) * 64 + h]);
}

// ---------------------------------------------------------------------------
// transpose+convert: out[z][c][r] = bf16(in[z][r][c])
// ---------------------------------------------------------------------------
__global__ __launch_bounds__(256) void trans_kernel(const float* __restrict__ in,
                                                    short* __restrict__ out,
                                                    int R, int C) {
    long zo = (long)blockIdx.y * R * C;
    int idx = blockIdx.x * 256 + threadIdx.x;
    if (idx >= R * C) return;
    int c = idx / R, r = idx - c * R;
    out[zo + idx] = f2b(in[zo + (long)r * C + c]);
}

// ---------------------------------------------------------------------------
// prep: hw2[e][k][t] = sum_o exp_w2[e][k][o] * head_w[t][o]  (4*256*2 f32)
//       hc[e][t]     = sum_o exp_b2[e][o] * head_w[t][o]
// ---------------------------------------------------------------------------
__global__ __launch_bounds__(256) void prep_hw2(const float* __restrict__ w2,
                                                const float* __restrict__ b2,
                                                const float* __restrict__ head_w,
                                                float* __restrict__ hw2,
                                                float* __restrict__ hc) {
    __shared__ float hw[256];
    const int e = blockIdx.x, t = threadIdx.x;
    hw[t] = head_w[t];
    __syncthreads();
    const float* row = &w2[((long)e * HH1 + t) * HH2];
    float s0 = 0.f, s1 = 0.f;
    #pragma unroll 8
    for (int o = 0; o < 128; o += 4) {
        float4 v = *reinterpret_cast<const float4*>(&row[o]);
        s0 += v.x * hw[o] + v.y * hw[o + 1] + v.z * hw[o + 2] + v.w * hw[o + 3];
        s1 += v.x * hw[128 + o] + v.y * hw[129 + o] + v.z * hw[130 + o] + v.w * hw[131 + o];
    }
    hw2[(((e << 8) + t) << 1) + 0] = s0;
    hw2[(((e << 8) + t) << 1) + 1] = s1;
    if (t < 2) {
        float s = 0.f;
        for (int o = 0; o < 128; ++o) s += b2[e * 128 + o] * hw[t * 128 + o];
        hc[e * 2 + t] = s;
    }
}

// ---------------------------------------------------------------------------
// K1: DIN attention (MFMA, q folded into B) + concat + LayerNorm1 -> x0
// hist staged ONCE: bf16 in LDS + bf16 corrections in registers (f32 exact
// to ~2^-18) so interest needs no second global gather.
// ---------------------------------------------------------------------------
__global__ __launch_bounds__(256, 8) void attn_kernel(
    const int* __restrict__ userId, const int* __restrict__ movieId,
    const int* __restrict__ seq, const float* __restrict__ dense,
    const float* __restrict__ emb_user, const float* __restrict__ emb_movie,
    const short* __restrict__ Wqpb, const short* __restrict__ WkFb,
    const short* __restrict__ WpFb,
    const float* __restrict__ att_b1, const float* __restrict__ att_w2,
    const float* __restrict__ att_b2,
    const float* __restrict__ in_gamma, const float* __restrict__ in_beta,
    float* __restrict__ x0f, short* __restrict__ x0b)
{
    __shared__ short hist[64 * 128];    // swizzled: byte = l*256 + ((d*2)^((l&7)<<4))
    __shared__ float qs[128];
    __shared__ int   seq_s[64];
    __shared__ float qconst[64];
    __shared__ float sp[4][64];
    __shared__ float probs[64];
    __shared__ float xrow[392];
    __shared__ float stats[2];

    const int b = blockIdx.x;
    const int t = threadIdx.x;
    const int lane = t & 63;
    const int w = t >> 6;

    if (t < 128) qs[t] = emb_movie[(long)movieId[b] * DE + t];
    if (t < 64)  seq_s[t] = (t < LL) ? seq[b * LL + t] : 0;
    __syncthreads();   // A

    // stage hist bf16 swizzled + keep bf16 corrections in registers
    const int g  = t >> 5;            // row-group 0..7
    const int d0 = (t & 31) << 2;     // fixed col group per thread
    short4v corr[8];
    #pragma unroll
    for (int i = 0; i < 8; ++i) {
        const int l = g + (i << 3);
        float4 v = make_float4(0.f, 0.f, 0.f, 0.f);
        if (l < LL)
            v = *reinterpret_cast<const float4*>(&emb_movie[(long)seq_s[l] * DE + d0]);
        short4v hv;
        hv[0] = f2b(v.x); hv[1] = f2b(v.y); hv[2] = f2b(v.z); hv[3] = f2b(v.w);
        corr[i][0] = f2b(v.x - b2f(hv[0]));
        corr[i][1] = f2b(v.y - b2f(hv[1]));
        corr[i][2] = f2b(v.z - b2f(hv[2]));
        corr[i][3] = f2b(v.w - b2f(hv[3]));
        const int byte = (l << 8) + ((d0 << 1) ^ ((l & 7) << 4));
        *reinterpret_cast<short4v*>(reinterpret_cast<char*>(hist) + byte) = hv;
    }

    // per-row B fragments: V[k][h] = Wk'[k][h] + q[k]*Wp[k][h] (bf16 tables)
    short8 bfrag[4];
    #pragma unroll
    for (int kt = 0; kt < 4; ++kt) {
        const int fo = ((((kt << 2) + w) << 6) | lane) << 3;
        short8 wk = *reinterpret_cast<const short8*>(&WkFb[fo]);
        short8 wp = *reinterpret_cast<const short8*>(&WpFb[fo]);
        const int kq = (kt << 5) + ((lane >> 4) << 3);
        #pragma unroll
        for (int j = 0; j < 8; ++j)
            bfrag[kt][j] = f2b(fmaf(qs[kq + j], b2f(wp[j]), b2f(wk[j])));
    }

    // qconst partial: wave w covers d in [32w, 32w+32)
    {
        float s = 0.f;
        const int dq = w << 5;
        #pragma unroll
        for (int dd = 0; dd < 32; ++dd)
            s = fmaf(qs[dq + dd], b2f(Wqpb[(dq + dd) * 64 + lane]), s);
        sp[w][lane] = s;
    }
    __syncthreads();   // B
    if (t < 64) qconst[t] = att_b1[t] + sp[0][t] + sp[1][t] + sp[2][t] + sp[3][t];
    __syncthreads();   // C

    // MFMA per m-tile, immediately reduced to score partials (low acc liveness)
    {
        const float qc  = qconst[(w << 4) + (lane & 15)];
        const float w2v = att_w2[(w << 4) + (lane & 15)];
        #pragma unroll
        for (int mt = 0; mt < 4; ++mt) {
            f32x4 acc;
            #pragma unroll
            for (int r = 0; r < 4; ++r) acc[r] = qc;
            const int row = (mt << 4) + (lane & 15);
            const int rbase = row << 8;
            const int swz = (row & 7) << 4;
            #pragma unroll
            for (int kt = 0; kt < 4; ++kt) {
                const int kbyte = (kt << 6) + ((lane >> 4) << 4);
                short8 a = *reinterpret_cast<const short8*>(
                    reinterpret_cast<char*>(hist) + rbase + (kbyte ^ swz));
                acc = __builtin_amdgcn_mfma_f32_16x16x32_bf16(a, bfrag[kt], acc, 0, 0, 0);
            }
            #pragma unroll
            for (int r = 0; r < 4; ++r) {
                float v = fmaxf(acc[r], 0.f) * w2v;
                v += __shfl_xor(v, 1); v += __shfl_xor(v, 2);
                v += __shfl_xor(v, 4); v += __shfl_xor(v, 8);
                if ((lane & 15) == 0)
                    sp[w][(mt << 4) + ((lane >> 4) << 2) + r] = v;
            }
        }
    }
    __syncthreads();   // D

    // masked softmax over l (threads 0..63); probs[l>=LL] = 0
    if (t < 64) {
        float sc = sp[0][t] + sp[1][t] + sp[2][t] + sp[3][t] + att_b2[0];
        float s = (t < LL) ? ((seq_s[t] > 0) ? sc : -1e9f) : -INFINITY;
        float m = s;
        #pragma unroll
        for (int off = 32; off > 0; off >>= 1) m = fmaxf(m, __shfl_xor(m, off));
        float e = (t < LL) ? __expf(s - m) : 0.f;
        float sum = e;
        #pragma unroll
        for (int off = 32; off > 0; off >>= 1) sum += __shfl_xor(sum, off);
        probs[t] = (t < LL) ? (e / sum) : 0.f;
    }
    __syncthreads();   // E

    // interest partials: LDS bf16 + register corrections (no global gather)
    float4 ps = make_float4(0.f, 0.f, 0.f, 0.f);
    #pragma unroll
    for (int i = 0; i < 8; ++i) {
        const int l = g + (i << 3);
        const int byte = (l << 8) + ((d0 << 1) ^ ((l & 7) << 4));
        short4v hv = *reinterpret_cast<const short4v*>(
            reinterpret_cast<const char*>(hist) + byte);
        const float p = probs[l];
        ps.x = fmaf(p, b2f(hv[0]) + b2f(corr[i][0]), ps.x);
        ps.y = fmaf(p, b2f(hv[1]) + b2f(corr[i][1]), ps.y);
        ps.z = fmaf(p, b2f(hv[2]) + b2f(corr[i][2]), ps.z);
        ps.w = fmaf(p, b2f(hv[3]) + b2f(corr[i][3]), ps.w);
    }
    ps.x += __shfl_xor(ps.x, 32); ps.y += __shfl_xor(ps.y, 32);
    ps.z += __shfl_xor(ps.z, 32); ps.w += __shfl_xor(ps.w, 32);
    float ue = (t < 128) ? emb_user[(long)userId[b] * DE + t] : 0.f;
    __syncthreads();   // F1: hist reads done, safe to overwrite as scratch
    float* scr = reinterpret_cast<float*>(hist);   // [4][128] f32
    if (lane < 32)
        *reinterpret_cast<float4*>(&scr[(w << 7) + ((lane & 31) << 2)]) = ps;
    __syncthreads();   // F2
    if (t < 128) {
        xrow[256 + t] = scr[t] + scr[128 + t] + scr[256 + t] + scr[384 + t];
        xrow[t] = ue;
        xrow[128 + t] = qs[t];
        if (t < 8) xrow[384 + t] = dense[b * 8 + t];
    }
    __syncthreads();   // G

    // LayerNorm over 392
    float v0 = xrow[t];
    float v1 = (t < 136) ? xrow[256 + t] : 0.f;
    float s2 = v0 + v1, q2 = v0 * v0 + v1 * v1;
    #pragma unroll
    for (int off = 32; off > 0; off >>= 1) {
        s2 += __shfl_xor(s2, off);
        q2 += __shfl_xor(q2, off);
    }
    if (lane == 0) { sp[0][w] = s2; sp[1][w] = q2; }
    __syncthreads();
    if (t == 0) {
        float S = sp[0][0] + sp[0][1] + sp[0][2] + sp[0][3];
        float Q = sp[1][0] + sp[1][1] + sp[1][2] + sp[1][3];
        float mean = S / (float)DD;
        float var = Q / (float)DD - mean * mean;
        stats[0] = mean;
        stats[1] = rsqrtf(var + 1e-5f);
    }
    __syncthreads();
    const float mean = stats[0], inv = stats[1];
    const long base = (long)b * DD;
    float o0 = (v0 - mean) * inv * in_gamma[t] + in_beta[t];
    x0f[base + t] = o0; x0b[base + t] = f2b(o0);
    if (t < 136) {
        float o1 = (v1 - mean) * inv * in_gamma[256 + t] + in_beta[256 + t];
        x0f[base + 256 + t] = o1; x0b[base + 256 + t] = f2b(o1);
    }
}

// ---------------------------------------------------------------------------
// bf16 MFMA GEMM, 2-phase double-buffered pipeline + chunked-XCD swizzle.
// out = f(A[M,K](bf16) @ WT[N,K]^T(bf16) + bias)
// MODE 0: +bias ; 1: relu(+bias) ; 2: cross: out = x0*(acc+bias)+xin
// 1-D grid, id m-major: id = mb*(NXB*NZB) + z*NXB + xb. grid%8 must be 0.
// ---------------------------------------------------------------------------
template<int MODE, int WF32, int WB16, int NXB, int NZB>
__global__ __launch_bounds__(256) void bgemm(
    const short* __restrict__ A, const short* __restrict__ WT,
    const float* __restrict__ bias,
    float* __restrict__ outF, short* __restrict__ outB,
    const float* __restrict__ x0, const float* __restrict__ xin,
    int M, int N, int K, long aZ, long wZ, long bZ, long oZ)
{
    __shared__ short As[2][64 * 64];   // swizzled: byte = r*128 + ((k*2)^((r&7)<<4))
    __shared__ short Bs[2][64 * 64];

    // chunked XCD swizzle (bijective: grid % 8 == 0)
    int id = blockIdx.x;
    const int qq = (int)gridDim.x >> 3;
    id = (id & 7) * qq + (id >> 3);
    const int mb  = id / (NXB * NZB);
    const int rem = id - mb * (NXB * NZB);
    const int z   = rem / NXB;
    const int xb  = rem - z * NXB;

    A += (long)z * aZ; WT += (long)z * wZ; bias += (long)z * bZ;
    const long oz = (long)z * oZ;

    const int t = threadIdx.x, w = t >> 6, lane = t & 63;
    const int m0 = mb * 64, n0 = xb * 64;
    const int sm = t >> 3, sk8 = (t & 7) << 3;   // staging: row, k-offset

    f32x4 acc[4];
    #pragma unroll
    for (int i = 0; i < 4; ++i) {
        #pragma unroll
        for (int r = 0; r < 4; ++r) acc[i][r] = 0.f;
    }

    const int nsteps = (K + 63) >> 6;
    short8 avr[2], bvr[2];

    auto loadr = [&](int k0) {
        #pragma unroll
        for (int i = 0; i < 2; ++i) {
            const int r = sm + (i << 5);
            short8 zv = {0, 0, 0, 0, 0, 0, 0, 0};
            avr[i] = zv; bvr[i] = zv;
            if (k0 + sk8 < K) {
                avr[i] = *reinterpret_cast<const short8*>(&A[(long)(m0 + r) * K + k0 + sk8]);
                if (n0 + r < N)
                    bvr[i] = *reinterpret_cast<const short8*>(&WT[(long)(n0 + r) * K + k0 + sk8]);
            }
        }
    };
    auto writelds = [&](int buf) {
        #pragma unroll
        for (int i = 0; i < 2; ++i) {
            const int r = sm + (i << 5);
            const int byte = (r << 7) + ((sk8 << 1) ^ ((r & 7) << 4));
            *reinterpret_cast<short8*>(reinterpret_cast<char*>(&As[buf][0]) + byte) = avr[i];
            *reinterpret_cast<short8*>(reinterpret_cast<char*>(&Bs[buf][0]) + byte) = bvr[i];
        }
    };

    loadr(0);
    writelds(0);
    __syncthreads();

    int cur = 0;
    for (int s = 0; s < nsteps; ++s) {
        if (s + 1 < nsteps) loadr((s + 1) << 6);   // issue early (hidden under MFMA)
        #pragma unroll
        for (int kt = 0; kt < 2; ++kt) {
            const int kbyte = (kt << 6) + ((lane >> 4) << 4);
            const int ar = (w << 4) + (lane & 15);
            short8 a = *reinterpret_cast<const short8*>(
                reinterpret_cast<char*>(&As[cur][0]) + (ar << 7) + (kbyte ^ ((ar & 7) << 4)));
            #pragma unroll
            for (int nt = 0; nt < 4; ++nt) {
                const int br = (nt << 4) + (lane & 15);
                short8 bb = *reinterpret_cast<const short8*>(
                    reinterpret_cast<char*>(&Bs[cur][0]) + (br << 7) + (kbyte ^ ((br & 7) << 4)));
                acc[nt] = __builtin_amdgcn_mfma_f32_16x16x32_bf16(a, bb, acc[nt], 0, 0, 0);
            }
        }
        if (s + 1 < nsteps) writelds(cur ^ 1);     // other buffer: no pre-barrier needed
        __syncthreads();
        cur ^= 1;
    }

    #pragma unroll
    for (int nt = 0; nt < 4; ++nt) {
        const int col = n0 + (nt << 4) + (lane & 15);
        if (col < N) {
            const float bv = bias[col];
            #pragma unroll
            for (int r = 0; r < 4; ++r) {
                const int row = m0 + (w << 4) + ((lane >> 4) << 2) + r;
                float v = acc[nt][r] + bv;
                if (MODE == 1) v = fmaxf(v, 0.f);
                const long o = (long)row * N + col;
                if (MODE == 2) v = x0[o] * v + xin[o];
                if (WF32) outF[oz + o] = v;
                if (WB16) outB[oz + o] = f2b(v);
            }
        }
    }
}

// ---------------------------------------------------------------------------
// LayerNorm over 392 (block per row), f32 + bf16 outputs
// ---------------------------------------------------------------------------
__global__ __launch_bounds__(256) void ln_kernel(
    const float* __restrict__ in,
    const float* __restrict__ gamma, const float* __restrict__ beta,
    float* __restrict__ outF, short* __restrict__ outB)
{
    __shared__ float red[2][4];
    __shared__ float stats[2];
    const int b = blockIdx.x, t = threadIdx.x, lane = t & 63, w = t >> 6;
    const long base = (long)b * DD;
    float v0 = in[base + t];
    float v1 = (t < 136) ? in[base + 256 + t] : 0.f;
    float s = v0 + v1, q2 = v0 * v0 + v1 * v1;
    #pragma unroll
    for (int off = 32; off > 0; off >>= 1) {
        s += __shfl_xor(s, off);
        q2 += __shfl_xor(q2, off);
    }
    if (lane == 0) { red[0][w] = s; red[1][w] = q2; }
    __syncthreads();
    if (t == 0) {
        float S = red[0][0] + red[0][1] + red[0][2] + red[0][3];
        float Q = red[1][0] + red[1][1] + red[1][2] + red[1][3];
        float mean = S / (float)DD;
        float var = Q / (float)DD - mean * mean;
        stats[0] = mean;
        stats[1] = rsqrtf(var + 1e-5f);
    }
    __syncthreads();
    const float mean = stats[0], inv = stats[1];
    float o0 = (v0 - mean) * inv * gamma[t] + beta[t];
    outF[base + t] = o0; outB[base + t] = f2b(o0);
    if (t < 136) {
        float o1 = (v1 - mean) * inv * gamma[256 + t] + beta[256 + t];
        outF[base + 256 + t] = o1; outB[base + 256 + t] = f2b(o1);
    }
}

// ---------------------------------------------------------------------------
// K3: gates (from x f32) + expert-head dots (from h1 bf16 via hw2) + mix.
// One wave per row, 4 rows/block.
// ---------------------------------------------------------------------------
__global__ __launch_bounds__(256) void final_kernel(
    const float* __restrict__ x, const short* __restrict__ h1,
    const float* __restrict__ hw2, const float* __restrict__ hc,
    const float* __restrict__ gate_w, const float* __restrict__ gate_b,
    const float* __restrict__ head_b, float* __restrict__ out)
{
    const int t = threadIdx.x, lane = t & 63, w = t >> 6;
    const int b = blockIdx.x * 4 + w;
    const float* xr = x + (long)b * DD;

    float xv[7];
    #pragma unroll
    for (int i = 0; i < 7; ++i) {
        int d = lane + (i << 6);
        xv[i] = (d < DD) ? xr[d] : 0.f;
    }

    float gl[8] = {0.f, 0.f, 0.f, 0.f, 0.f, 0.f, 0.f, 0.f};
    #pragma unroll
    for (int i = 0; i < 7; ++i) {
        int d = lane + (i << 6);
        if (d < DD) {
            float4 g0 = *reinterpret_cast<const float4*>(&gate_w[d << 2]);
            float4 g1 = *reinterpret_cast<const float4*>(&gate_w[1568 + (d << 2)]);
            gl[0] = fmaf(xv[i], g0.x, gl[0]); gl[1] = fmaf(xv[i], g0.y, gl[1]);
            gl[2] = fmaf(xv[i], g0.z, gl[2]); gl[3] = fmaf(xv[i], g0.w, gl[3]);
            gl[4] = fmaf(xv[i], g1.x, gl[4]); gl[5] = fmaf(xv[i], g1.y, gl[5]);
            gl[6] = fmaf(xv[i], g1.z, gl[6]); gl[7] = fmaf(xv[i], g1.w, gl[7]);
        }
    }

    float ed[8];
    #pragma unroll
    for (int e = 0; e < 4; ++e) {
        short4v hv = *reinterpret_cast<const short4v*>(
            &h1[((long)e * BB + b) * HH1 + (lane << 2)]);
        const float* hwp = &hw2[(((e << 8) + (lane << 2))) << 1];
        float4 w01 = *reinterpret_cast<const float4*>(hwp);
        float4 w23 = *reinterpret_cast<const float4*>(hwp + 4);
        float h0 = b2f(hv[0]), h1f = b2f(hv[1]), h2 = b2f(hv[2]), h3 = b2f(hv[3]);
        ed[e]     = fmaf(h0, w01.x, fmaf(h1f, w01.z, fmaf(h2, w23.x, h3 * w23.z)));
        ed[4 + e] = fmaf(h0, w01.y, fmaf(h1f, w01.w, fmaf(h2, w23.y, h3 * w23.w)));
    }

    #pragma unroll
    for (int v = 0; v < 8; ++v) {
        #pragma unroll
        for (int off = 32; off > 0; off >>= 1) {
            gl[v] += __shfl_xor(gl[v], off);
            ed[v] += __shfl_xor(ed[v], off);
        }
    }

    if (lane == 0) {
        float res[2];
        #pragma unroll
        for (int tt = 0; tt < 2; ++tt) {
            float lv[4], m = -1e30f;
            #pragma unroll
            for (int e = 0; e < 4; ++e) {
                lv[e] = gl[tt * 4 + e] + gate_b[tt * 4 + e];
                m = fmaxf(m, lv[e]);
            }
            float sum = 0.f, acc = 0.f;
            #pragma unroll
            for (int e = 0; e < 4; ++e) { lv[e] = __expf(lv[e] - m); sum += lv[e]; }
            #pragma unroll
            for (int e = 0; e < 4; ++e)
                acc = fmaf(lv[e], ed[tt * 4 + e] + hc[e * 2 + tt], acc);
            res[tt] = head_b[tt] + acc / sum;
        }
        out[b] = res[0];
        out[BB + b] = res[1];
    }
}

// ---------------------------------------------------------------------------
extern "C" void kernel_launch(void* const* d_in, const int* in_sizes, int n_in,
                              void* d_out, int out_size, void* d_ws, size_t ws_size,
                              hipStream_t stream) {
    const int*   userId    = (const int*)d_in[0];
    const int*   movieId   = (const int*)d_in[1];
    const int*   seq       = (const int*)d_in[2];
    const float* dense     = (const float*)d_in[3];
    const float* emb_user  = (const float*)d_in[4];
    const float* emb_movie = (const float*)d_in[5];
    const float* att_w1    = (const float*)d_in[6];
    const float* att_b1    = (const float*)d_in[7];
    const float* att_w2    = (const float*)d_in[8];
    const float* att_b2    = (const float*)d_in[9];
    const float* in_gamma  = (const float*)d_in[10];
    const float* in_beta   = (const float*)d_in[11];
    const float* cr_gamma  = (const float*)d_in[12];
    const float* cr_beta   = (const float*)d_in[13];
    const float* cross_W   = (const float*)d_in[14];
    const float* cross_b   = (const float*)d_in[15];
    const float* exp_w1    = (const float*)d_in[16];
    const float* exp_b1    = (const float*)d_in[17];
    const float* exp_w2    = (const float*)d_in[18];
    const float* exp_b2    = (const float*)d_in[19];
    const float* gate_w    = (const float*)d_in[20];
    const float* gate_b    = (const float*)d_in[21];
    const float* head_w    = (const float*)d_in[22];
    const float* head_b    = (const float*)d_in[23];
    float* outp = (float*)d_out;

    char* p = (char*)d_ws;
    auto alloc = [&](size_t bytes) -> char* {
        char* r = p; p += (bytes + 255) & ~(size_t)255; return r;
    };
    short* Wqpb = (short*)alloc(8192 * 2);
    short* WkFb = (short*)alloc(8192 * 2);
    short* WpFb = (short*)alloc(8192 * 2);
    float* hw2 = (float*)alloc(2048 * 4);
    float* hc  = (float*)alloc(8 * 4);
    short* WTc = (short*)alloc((size_t)3 * 392 * 392 * 2);
    short* WT1 = (short*)alloc((size_t)4 * 256 * 392 * 2);
    float* x0f = (float*)alloc((size_t)BB * DD * 4);
    short* x0b = (short*)alloc((size_t)BB * DD * 2);
    float* xAf = (float*)alloc((size_t)BB * DD * 4);
    short* xAb = (short*)alloc((size_t)BB * DD * 2);
    float* xBf = (float*)alloc((size_t)BB * DD * 4);
    short* xBb = (short*)alloc((size_t)BB * DD * 2);
    short* h1b = (short*)alloc((size_t)4 * BB * HH1 * 2);

    prep_wqp<<<32, 256, 0, stream>>>(att_w1, Wqpb);
    prep_wkwp<<<32, 256, 0, stream>>>(att_w1, WkFb, WpFb);
    trans_kernel<<<dim3(601, 3), 256, 0, stream>>>(cross_W, WTc, 392, 392);
    trans_kernel<<<dim3(392, 4), 256, 0, stream>>>(exp_w1, WT1, 392, 256);
    prep_hw2<<<4, 256, 0, stream>>>(exp_w2, exp_b2, head_w, hw2, hc);

    attn_kernel<<<BB, 256, 0, stream>>>(userId, movieId, seq, dense,
                                        emb_user, emb_movie, Wqpb, WkFb, WpFb,
                                        att_b1, att_w2, att_b2,
                                        in_gamma, in_beta, x0f, x0b);

    // CrossNetV2: grid = 128 m-blocks * 7 n-blocks = 896 (%8==0)
    bgemm<2, 1, 1, 7, 1><<<896, 256, 0, stream>>>(x0b, WTc, cross_b, xAf, xAb,
                                                  x0f, x0f, BB, DD, DD, 0, 0, 0, 0);
    bgemm<2, 1, 1, 7, 1><<<896, 256, 0, stream>>>(xAb, WTc + 392 * 392, cross_b + 392,
                                                  xBf, xBb, x0f, xAf, BB, DD, DD, 0, 0, 0, 0);
    bgemm<2, 1, 0, 7, 1><<<896, 256, 0, stream>>>(xBb, WTc + 2 * 392 * 392, cross_b + 784,
                                                  xAf, nullptr, x0f, xBf, BB, DD, DD, 0, 0, 0, 0);

    // LN2: xAf -> xBf (+bf16)
    ln_kernel<<<BB, 256, 0, stream>>>(xAf, cr_gamma, cr_beta, xBf, xBb);

    // Experts layer 1: h1 = relu(x @ w1 + b1)  [E][B][256] bf16
    // grid = 128 m-blocks * 4 z * 4 n-blocks = 2048 (%8==0)
    bgemm<1, 0, 1, 4, 4><<<2048, 256, 0, stream>>>(
        xBb, WT1, exp_b1, nullptr, h1b, nullptr, nullptr,
        BB, HH1, DD, 0, (long)HH1 * DD, HH1, (long)BB * HH1);

    // gates + expert-head dots + mix -> logits [2][B]
    final_kernel<<<BB / 4, 256, 0, stream>>>(xBf, h1b, hw2, hc,
                                             gate_w, gate_b, head_b, outp);

    (void)in_sizes; (void)n_in; (void)out_size; (void)ws_size;
}

// Round 5
// 189.824 us; speedup vs baseline: 1.4093x; 1.4093x over previous
//
#include <hip/hip_runtime.h>
#include <hip/hip_bf16.h>

typedef short short8 __attribute__((ext_vector_type(8)));
typedef short short4v __attribute__((ext_vector_type(4)));
typedef float f32x4 __attribute__((ext_vector_type(4)));

constexpr int BB = 8192;   // batch
constexpr int LL = 50;     // seq len
constexpr int DE = 128;    // emb dim
constexpr int DD = 392;    // total input dim
constexpr int HH1 = 256;
constexpr int HH2 = 128;

__device__ __forceinline__ short f2b(float x) {
    __hip_bfloat16 h = __float2bfloat16(x);   // RNE
    return __builtin_bit_cast(short, h);
}
__device__ __forceinline__ float b2f(short v) {
    unsigned u = ((unsigned)(unsigned short)v) << 16;
    return __builtin_bit_cast(float, u);
}

// ---------------------------------------------------------------------------
// prep: Wq' = W1q + W1(q-k)  (bf16, [128][64])
// ---------------------------------------------------------------------------
__global__ __launch_bounds__(256) void prep_wqp(const float* __restrict__ w1,
                                                short* __restrict__ Wqpb) {
    int idx = blockIdx.x * 256 + threadIdx.x;       // d*64+h, 8192
    Wqpb[idx] = f2b(w1[idx] + w1[idx + 16384]);
}

// ---------------------------------------------------------------------------
// prep: Wk' = W1k - W1d and Wp, bf16 in MFMA B-fragment order:
// o = [kt(4)][nt(4)][lane(64)][e(8)]; element = W[k][h],
// k = kt*32 + (lane>>4)*8 + e, h = nt*16 + (lane&15)
// ---------------------------------------------------------------------------
__global__ __launch_bounds__(256) void prep_wkwp(const float* __restrict__ w1,
                                                 short* __restrict__ WkFb,
                                                 short* __restrict__ WpFb) {
    int o = blockIdx.x * 256 + threadIdx.x;         // 8192
    int e = o & 7, lane = (o >> 3) & 63, nt = (o >> 9) & 3, kt = o >> 11;
    int k = (kt << 5) + ((lane >> 4) << 3) + e;
    int h = (nt << 4) + (lane & 15);
    WkFb[o] = f2b(w1[(128 + k) * 64 + h] - w1[(256 + k) * 64 + h]);
    WpFb[o] = f2b(w1[(384 + k) * 64 + h]);
}

// ---------------------------------------------------------------------------
// transpose+convert: out[z][c][r] = bf16(in[z][r][c])
// ---------------------------------------------------------------------------
__global__ __launch_bounds__(256) void trans_kernel(const float* __restrict__ in,
                                                    short* __restrict__ out,
                                                    int R, int C) {
    long zo = (long)blockIdx.y * R * C;
    int idx = blockIdx.x * 256 + threadIdx.x;
    if (idx >= R * C) return;
    int c = idx / R, r = idx - c * R;
    out[zo + idx] = f2b(in[zo + (long)r * C + c]);
}

// ---------------------------------------------------------------------------
// prep: hw2[e][k][t] = sum_o exp_w2[e][k][o] * head_w[t][o]  (4*256*2 f32)
//       hc[e][t]     = sum_o exp_b2[e][o] * head_w[t][o]
// ---------------------------------------------------------------------------
__global__ __launch_bounds__(256) void prep_hw2(const float* __restrict__ w2,
                                                const float* __restrict__ b2,
                                                const float* __restrict__ head_w,
                                                float* __restrict__ hw2,
                                                float* __restrict__ hc) {
    __shared__ float hw[256];
    const int e = blockIdx.x, t = threadIdx.x;
    hw[t] = head_w[t];
    __syncthreads();
    const float* row = &w2[((long)e * HH1 + t) * HH2];
    float s0 = 0.f, s1 = 0.f;
    #pragma unroll 8
    for (int o = 0; o < 128; o += 4) {
        float4 v = *reinterpret_cast<const float4*>(&row[o]);
        s0 += v.x * hw[o] + v.y * hw[o + 1] + v.z * hw[o + 2] + v.w * hw[o + 3];
        s1 += v.x * hw[128 + o] + v.y * hw[129 + o] + v.z * hw[130 + o] + v.w * hw[131 + o];
    }
    hw2[(((e << 8) + t) << 1) + 0] = s0;
    hw2[(((e << 8) + t) << 1) + 1] = s1;
    if (t < 2) {
        float s = 0.f;
        for (int o = 0; o < 128; ++o) s += b2[e * 128 + o] * hw[t * 128 + o];
        hc[e * 2 + t] = s;
    }
}

// ---------------------------------------------------------------------------
// K1: DIN attention (MFMA, q folded into B) + concat + LayerNorm1 -> x0
// hist staged ONCE as bf16 in LDS; interest computed from the same LDS copy
// (no corrections, no second gather, no register spill).
// ---------------------------------------------------------------------------
__global__ __launch_bounds__(256, 8) void attn_kernel(
    const int* __restrict__ userId, const int* __restrict__ movieId,
    const int* __restrict__ seq, const float* __restrict__ dense,
    const float* __restrict__ emb_user, const float* __restrict__ emb_movie,
    const short* __restrict__ Wqpb, const short* __restrict__ WkFb,
    const short* __restrict__ WpFb,
    const float* __restrict__ att_b1, const float* __restrict__ att_w2,
    const float* __restrict__ att_b2,
    const float* __restrict__ in_gamma, const float* __restrict__ in_beta,
    float* __restrict__ x0f, short* __restrict__ x0b)
{
    __shared__ short hist[64 * 128];    // swizzled: byte = l*256 + ((d*2)^((l&7)<<4))
    __shared__ float qs[128];
    __shared__ int   seq_s[64];
    __shared__ float qconst[64];
    __shared__ float sp[4][64];
    __shared__ float probs[64];
    __shared__ float xrow[392];
    __shared__ float stats[2];

    const int b = blockIdx.x;
    const int t = threadIdx.x;
    const int lane = t & 63;
    const int w = t >> 6;

    if (t < 128) qs[t] = emb_movie[(long)movieId[b] * DE + t];
    if (t < 64)  seq_s[t] = (t < LL) ? seq[b * LL + t] : 0;
    __syncthreads();   // A

    // stage hist bf16 swizzled; rows >= LL zero
    const int g  = t >> 5;            // row-group 0..7
    const int d0 = (t & 31) << 2;     // fixed col group per thread
    #pragma unroll
    for (int i = 0; i < 8; ++i) {
        const int l = g + (i << 3);
        float4 v = make_float4(0.f, 0.f, 0.f, 0.f);
        if (l < LL)
            v = *reinterpret_cast<const float4*>(&emb_movie[(long)seq_s[l] * DE + d0]);
        short4v hv;
        hv[0] = f2b(v.x); hv[1] = f2b(v.y); hv[2] = f2b(v.z); hv[3] = f2b(v.w);
        const int byte = (l << 8) + ((d0 << 1) ^ ((l & 7) << 4));
        *reinterpret_cast<short4v*>(reinterpret_cast<char*>(hist) + byte) = hv;
    }

    // hoisted independent gathers (latency hides under bfrag/qconst/MFMA)
    float ue = (t < 128) ? emb_user[(long)userId[b] * DE + t] : 0.f;
    float dv = (t < 8) ? dense[b * 8 + t] : 0.f;

    // per-row B fragments: V[k][h] = Wk'[k][h] + q[k]*Wp[k][h] (bf16 tables)
    short8 bfrag[4];
    #pragma unroll
    for (int kt = 0; kt < 4; ++kt) {
        const int fo = ((((kt << 2) + w) << 6) | lane) << 3;
        short8 wk = *reinterpret_cast<const short8*>(&WkFb[fo]);
        short8 wp = *reinterpret_cast<const short8*>(&WpFb[fo]);
        const int kq = (kt << 5) + ((lane >> 4) << 3);
        #pragma unroll
        for (int j = 0; j < 8; ++j)
            bfrag[kt][j] = f2b(fmaf(qs[kq + j], b2f(wp[j]), b2f(wk[j])));
    }

    // qconst partial: wave w covers d in [32w, 32w+32)
    {
        float s = 0.f;
        const int dq = w << 5;
        #pragma unroll
        for (int dd = 0; dd < 32; ++dd)
            s = fmaf(qs[dq + dd], b2f(Wqpb[(dq + dd) * 64 + lane]), s);
        sp[w][lane] = s;
    }
    __syncthreads();   // B
    if (t < 64) qconst[t] = att_b1[t] + sp[0][t] + sp[1][t] + sp[2][t] + sp[3][t];
    __syncthreads();   // C

    // MFMA per m-tile, immediately reduced to score partials (low acc liveness)
    {
        const float qc  = qconst[(w << 4) + (lane & 15)];
        const float w2v = att_w2[(w << 4) + (lane & 15)];
        #pragma unroll
        for (int mt = 0; mt < 4; ++mt) {
            f32x4 acc;
            #pragma unroll
            for (int r = 0; r < 4; ++r) acc[r] = qc;
            const int row = (mt << 4) + (lane & 15);
            const int rbase = row << 8;
            const int swz = (row & 7) << 4;
            #pragma unroll
            for (int kt = 0; kt < 4; ++kt) {
                const int kbyte = (kt << 6) + ((lane >> 4) << 4);
                short8 a = *reinterpret_cast<const short8*>(
                    reinterpret_cast<char*>(hist) + rbase + (kbyte ^ swz));
                acc = __builtin_amdgcn_mfma_f32_16x16x32_bf16(a, bfrag[kt], acc, 0, 0, 0);
            }
            #pragma unroll
            for (int r = 0; r < 4; ++r) {
                float v = fmaxf(acc[r], 0.f) * w2v;
                v += __shfl_xor(v, 1); v += __shfl_xor(v, 2);
                v += __shfl_xor(v, 4); v += __shfl_xor(v, 8);
                if ((lane & 15) == 0)
                    sp[w][(mt << 4) + ((lane >> 4) << 2) + r] = v;
            }
        }
    }
    __syncthreads();   // D

    // masked softmax over l (threads 0..63); probs[l>=LL] = 0
    if (t < 64) {
        float sc = sp[0][t] + sp[1][t] + sp[2][t] + sp[3][t] + att_b2[0];
        float s = (t < LL) ? ((seq_s[t] > 0) ? sc : -1e9f) : -INFINITY;
        float m = s;
        #pragma unroll
        for (int off = 32; off > 0; off >>= 1) m = fmaxf(m, __shfl_xor(m, off));
        float e = (t < LL) ? __expf(s - m) : 0.f;
        float sum = e;
        #pragma unroll
        for (int off = 32; off > 0; off >>= 1) sum += __shfl_xor(sum, off);
        probs[t] = (t < LL) ? (e / sum) : 0.f;
    }
    __syncthreads();   // E

    // interest partials from the LDS bf16 hist (no global re-gather)
    float4 ps = make_float4(0.f, 0.f, 0.f, 0.f);
    #pragma unroll
    for (int i = 0; i < 8; ++i) {
        const int l = g + (i << 3);
        const int byte = (l << 8) + ((d0 << 1) ^ ((l & 7) << 4));
        short4v hv = *reinterpret_cast<const short4v*>(
            reinterpret_cast<const char*>(hist) + byte);
        const float p = probs[l];
        ps.x = fmaf(p, b2f(hv[0]), ps.x);
        ps.y = fmaf(p, b2f(hv[1]), ps.y);
        ps.z = fmaf(p, b2f(hv[2]), ps.z);
        ps.w = fmaf(p, b2f(hv[3]), ps.w);
    }
    ps.x += __shfl_xor(ps.x, 32); ps.y += __shfl_xor(ps.y, 32);
    ps.z += __shfl_xor(ps.z, 32); ps.w += __shfl_xor(ps.w, 32);
    __syncthreads();   // F1: all hist reads done, safe to reuse as scratch
    float* scr = reinterpret_cast<float*>(hist);   // [4][128] f32
    if (lane < 32)
        *reinterpret_cast<float4*>(&scr[(w << 7) + ((lane & 31) << 2)]) = ps;
    __syncthreads();   // F2
    if (t < 128) {
        xrow[256 + t] = scr[t] + scr[128 + t] + scr[256 + t] + scr[384 + t];
        xrow[t] = ue;
        xrow[128 + t] = qs[t];
        if (t < 8) xrow[384 + t] = dv;
    }
    __syncthreads();   // G

    // LayerNorm over 392
    float v0 = xrow[t];
    float v1 = (t < 136) ? xrow[256 + t] : 0.f;
    float s2 = v0 + v1, q2 = v0 * v0 + v1 * v1;
    #pragma unroll
    for (int off = 32; off > 0; off >>= 1) {
        s2 += __shfl_xor(s2, off);
        q2 += __shfl_xor(q2, off);
    }
    if (lane == 0) { sp[0][w] = s2; sp[1][w] = q2; }
    __syncthreads();
    if (t == 0) {
        float S = sp[0][0] + sp[0][1] + sp[0][2] + sp[0][3];
        float Q = sp[1][0] + sp[1][1] + sp[1][2] + sp[1][3];
        float mean = S / (float)DD;
        float var = Q / (float)DD - mean * mean;
        stats[0] = mean;
        stats[1] = rsqrtf(var + 1e-5f);
    }
    __syncthreads();
    const float mean = stats[0], inv = stats[1];
    const long base = (long)b * DD;
    float o0 = (v0 - mean) * inv * in_gamma[t] + in_beta[t];
    x0f[base + t] = o0; x0b[base + t] = f2b(o0);
    if (t < 136) {
        float o1 = (v1 - mean) * inv * in_gamma[256 + t] + in_beta[256 + t];
        x0f[base + 256 + t] = o1; x0b[base + 256 + t] = f2b(o1);
    }
}

// ---------------------------------------------------------------------------
// bf16 MFMA GEMM, 2-phase double-buffered pipeline + chunked-XCD swizzle.
// out = f(A[M,K](bf16) @ WT[N,K]^T(bf16) + bias)
// MODE 0: +bias ; 1: relu(+bias) ; 2: cross: out = x0*(acc+bias)+xin
// 1-D grid, id m-major: id = mb*(NXB*NZB) + z*NXB + xb. grid%8 must be 0.
// ---------------------------------------------------------------------------
template<int MODE, int WF32, int WB16, int NXB, int NZB>
__global__ __launch_bounds__(256) void bgemm(
    const short* __restrict__ A, const short* __restrict__ WT,
    const float* __restrict__ bias,
    float* __restrict__ outF, short* __restrict__ outB,
    const float* __restrict__ x0, const float* __restrict__ xin,
    int M, int N, int K, long aZ, long wZ, long bZ, long oZ)
{
    __shared__ short As[2][64 * 64];   // swizzled: byte = r*128 + ((k*2)^((r&7)<<4))
    __shared__ short Bs[2][64 * 64];

    // chunked XCD swizzle (bijective: grid % 8 == 0)
    int id = blockIdx.x;
    const int qq = (int)gridDim.x >> 3;
    id = (id & 7) * qq + (id >> 3);
    const int mb  = id / (NXB * NZB);
    const int rem = id - mb * (NXB * NZB);
    const int z   = rem / NXB;
    const int xb  = rem - z * NXB;

    A += (long)z * aZ; WT += (long)z * wZ; bias += (long)z * bZ;
    const long oz = (long)z * oZ;

    const int t = threadIdx.x, w = t >> 6, lane = t & 63;
    const int m0 = mb * 64, n0 = xb * 64;
    const int sm = t >> 3, sk8 = (t & 7) << 3;   // staging: row, k-offset

    f32x4 acc[4];
    #pragma unroll
    for (int i = 0; i < 4; ++i) {
        #pragma unroll
        for (int r = 0; r < 4; ++r) acc[i][r] = 0.f;
    }

    const int nsteps = (K + 63) >> 6;
    short8 avr[2], bvr[2];

    auto loadr = [&](int k0) {
        #pragma unroll
        for (int i = 0; i < 2; ++i) {
            const int r = sm + (i << 5);
            short8 zv = {0, 0, 0, 0, 0, 0, 0, 0};
            avr[i] = zv; bvr[i] = zv;
            if (k0 + sk8 < K) {
                avr[i] = *reinterpret_cast<const short8*>(&A[(long)(m0 + r) * K + k0 + sk8]);
                if (n0 + r < N)
                    bvr[i] = *reinterpret_cast<const short8*>(&WT[(long)(n0 + r) * K + k0 + sk8]);
            }
        }
    };
    auto writelds = [&](int buf) {
        #pragma unroll
        for (int i = 0; i < 2; ++i) {
            const int r = sm + (i << 5);
            const int byte = (r << 7) + ((sk8 << 1) ^ ((r & 7) << 4));
            *reinterpret_cast<short8*>(reinterpret_cast<char*>(&As[buf][0]) + byte) = avr[i];
            *reinterpret_cast<short8*>(reinterpret_cast<char*>(&Bs[buf][0]) + byte) = bvr[i];
        }
    };

    loadr(0);
    writelds(0);
    __syncthreads();

    int cur = 0;
    for (int s = 0; s < nsteps; ++s) {
        if (s + 1 < nsteps) loadr((s + 1) << 6);   // issue early (hidden under MFMA)
        #pragma unroll
        for (int kt = 0; kt < 2; ++kt) {
            const int kbyte = (kt << 6) + ((lane >> 4) << 4);
            const int ar = (w << 4) + (lane & 15);
            short8 a = *reinterpret_cast<const short8*>(
                reinterpret_cast<char*>(&As[cur][0]) + (ar << 7) + (kbyte ^ ((ar & 7) << 4)));
            #pragma unroll
            for (int nt = 0; nt < 4; ++nt) {
                const int br = (nt << 4) + (lane & 15);
                short8 bb = *reinterpret_cast<const short8*>(
                    reinterpret_cast<char*>(&Bs[cur][0]) + (br << 7) + (kbyte ^ ((br & 7) << 4)));
                acc[nt] = __builtin_amdgcn_mfma_f32_16x16x32_bf16(a, bb, acc[nt], 0, 0, 0);
            }
        }
        if (s + 1 < nsteps) writelds(cur ^ 1);     // other buffer: no pre-barrier needed
        __syncthreads();
        cur ^= 1;
    }

    #pragma unroll
    for (int nt = 0; nt < 4; ++nt) {
        const int col = n0 + (nt << 4) + (lane & 15);
        if (col < N) {
            const float bv = bias[col];
            #pragma unroll
            for (int r = 0; r < 4; ++r) {
                const int row = m0 + (w << 4) + ((lane >> 4) << 2) + r;
                float v = acc[nt][r] + bv;
                if (MODE == 1) v = fmaxf(v, 0.f);
                const long o = (long)row * N + col;
                if (MODE == 2) v = x0[o] * v + xin[o];
                if (WF32) outF[oz + o] = v;
                if (WB16) outB[oz + o] = f2b(v);
            }
        }
    }
}

// ---------------------------------------------------------------------------
// LayerNorm over 392 (block per row), f32 + bf16 outputs
// ---------------------------------------------------------------------------
__global__ __launch_bounds__(256) void ln_kernel(
    const float* __restrict__ in,
    const float* __restrict__ gamma, const float* __restrict__ beta,
    float* __restrict__ outF, short* __restrict__ outB)
{
    __shared__ float red[2][4];
    __shared__ float stats[2];
    const int b = blockIdx.x, t = threadIdx.x, lane = t & 63, w = t >> 6;
    const long base = (long)b * DD;
    float v0 = in[base + t];
    float v1 = (t < 136) ? in[base + 256 + t] : 0.f;
    float s = v0 + v1, q2 = v0 * v0 + v1 * v1;
    #pragma unroll
    for (int off = 32; off > 0; off >>= 1) {
        s += __shfl_xor(s, off);
        q2 += __shfl_xor(q2, off);
    }
    if (lane == 0) { red[0][w] = s; red[1][w] = q2; }
    __syncthreads();
    if (t == 0) {
        float S = red[0][0] + red[0][1] + red[0][2] + red[0][3];
        float Q = red[1][0] + red[1][1] + red[1][2] + red[1][3];
        float mean = S / (float)DD;
        float var = Q / (float)DD - mean * mean;
        stats[0] = mean;
        stats[1] = rsqrtf(var + 1e-5f);
    }
    __syncthreads();
    const float mean = stats[0], inv = stats[1];
    float o0 = (v0 - mean) * inv * gamma[t] + beta[t];
    outF[base + t] = o0; outB[base + t] = f2b(o0);
    if (t < 136) {
        float o1 = (v1 - mean) * inv * gamma[256 + t] + beta[256 + t];
        outF[base + 256 + t] = o1; outB[base + 256 + t] = f2b(o1);
    }
}

// ---------------------------------------------------------------------------
// K3: gates (from x f32) + expert-head dots (from h1 bf16 via hw2) + mix.
// One wave per row, 4 rows/block.
// ---------------------------------------------------------------------------
__global__ __launch_bounds__(256) void final_kernel(
    const float* __restrict__ x, const short* __restrict__ h1,
    const float* __restrict__ hw2, const float* __restrict__ hc,
    const float* __restrict__ gate_w, const float* __restrict__ gate_b,
    const float* __restrict__ head_b, float* __restrict__ out)
{
    const int t = threadIdx.x, lane = t & 63, w = t >> 6;
    const int b = blockIdx.x * 4 + w;
    const float* xr = x + (long)b * DD;

    float xv[7];
    #pragma unroll
    for (int i = 0; i < 7; ++i) {
        int d = lane + (i << 6);
        xv[i] = (d < DD) ? xr[d] : 0.f;
    }

    float gl[8] = {0.f, 0.f, 0.f, 0.f, 0.f, 0.f, 0.f, 0.f};
    #pragma unroll
    for (int i = 0; i < 7; ++i) {
        int d = lane + (i << 6);
        if (d < DD) {
            float4 g0 = *reinterpret_cast<const float4*>(&gate_w[d << 2]);
            float4 g1 = *reinterpret_cast<const float4*>(&gate_w[1568 + (d << 2)]);
            gl[0] = fmaf(xv[i], g0.x, gl[0]); gl[1] = fmaf(xv[i], g0.y, gl[1]);
            gl[2] = fmaf(xv[i], g0.z, gl[2]); gl[3] = fmaf(xv[i], g0.w, gl[3]);
            gl[4] = fmaf(xv[i], g1.x, gl[4]); gl[5] = fmaf(xv[i], g1.y, gl[5]);
            gl[6] = fmaf(xv[i], g1.z, gl[6]); gl[7] = fmaf(xv[i], g1.w, gl[7]);
        }
    }

    float ed[8];
    #pragma unroll
    for (int e = 0; e < 4; ++e) {
        short4v hv = *reinterpret_cast<const short4v*>(
            &h1[((long)e * BB + b) * HH1 + (lane << 2)]);
        const float* hwp = &hw2[(((e << 8) + (lane << 2))) << 1];
        float4 w01 = *reinterpret_cast<const float4*>(hwp);
        float4 w23 = *reinterpret_cast<const float4*>(hwp + 4);
        float h0 = b2f(hv[0]), h1f = b2f(hv[1]), h2 = b2f(hv[2]), h3 = b2f(hv[3]);
        ed[e]     = fmaf(h0, w01.x, fmaf(h1f, w01.z, fmaf(h2, w23.x, h3 * w23.z)));
        ed[4 + e] = fmaf(h0, w01.y, fmaf(h1f, w01.w, fmaf(h2, w23.y, h3 * w23.w)));
    }

    #pragma unroll
    for (int v = 0; v < 8; ++v) {
        #pragma unroll
        for (int off = 32; off > 0; off >>= 1) {
            gl[v] += __shfl_xor(gl[v], off);
            ed[v] += __shfl_xor(ed[v], off);
        }
    }

    if (lane == 0) {
        float res[2];
        #pragma unroll
        for (int tt = 0; tt < 2; ++tt) {
            float lv[4], m = -1e30f;
            #pragma unroll
            for (int e = 0; e < 4; ++e) {
                lv[e] = gl[tt * 4 + e] + gate_b[tt * 4 + e];
                m = fmaxf(m, lv[e]);
            }
            float sum = 0.f, acc = 0.f;
            #pragma unroll
            for (int e = 0; e < 4; ++e) { lv[e] = __expf(lv[e] - m); sum += lv[e]; }
            #pragma unroll
            for (int e = 0; e < 4; ++e)
                acc = fmaf(lv[e], ed[tt * 4 + e] + hc[e * 2 + tt], acc);
            res[tt] = head_b[tt] + acc / sum;
        }
        out[b] = res[0];
        out[BB + b] = res[1];
    }
}

// ---------------------------------------------------------------------------
extern "C" void kernel_launch(void* const* d_in, const int* in_sizes, int n_in,
                              void* d_out, int out_size, void* d_ws, size_t ws_size,
                              hipStream_t stream) {
    const int*   userId    = (const int*)d_in[0];
    const int*   movieId   = (const int*)d_in[1];
    const int*   seq       = (const int*)d_in[2];
    const float* dense     = (const float*)d_in[3];
    const float* emb_user  = (const float*)d_in[4];
    const float* emb_movie = (const float*)d_in[5];
    const float* att_w1    = (const float*)d_in[6];
    const float* att_b1    = (const float*)d_in[7];
    const float* att_w2    = (const float*)d_in[8];
    const float* att_b2    = (const float*)d_in[9];
    const float* in_gamma  = (const float*)d_in[10];
    const float* in_beta   = (const float*)d_in[11];
    const float* cr_gamma  = (const float*)d_in[12];
    const float* cr_beta   = (const float*)d_in[13];
    const float* cross_W   = (const float*)d_in[14];
    const float* cross_b   = (const float*)d_in[15];
    const float* exp_w1    = (const float*)d_in[16];
    const float* exp_b1    = (const float*)d_in[17];
    const float* exp_w2    = (const float*)d_in[18];
    const float* exp_b2    = (const float*)d_in[19];
    const float* gate_w    = (const float*)d_in[20];
    const float* gate_b    = (const float*)d_in[21];
    const float* head_w    = (const float*)d_in[22];
    const float* head_b    = (const float*)d_in[23];
    float* outp = (float*)d_out;

    char* p = (char*)d_ws;
    auto alloc = [&](size_t bytes) -> char* {
        char* r = p; p += (bytes + 255) & ~(size_t)255; return r;
    };
    short* Wqpb = (short*)alloc(8192 * 2);
    short* WkFb = (short*)alloc(8192 * 2);
    short* WpFb = (short*)alloc(8192 * 2);
    float* hw2 = (float*)alloc(2048 * 4);
    float* hc  = (float*)alloc(8 * 4);
    short* WTc = (short*)alloc((size_t)3 * 392 * 392 * 2);
    short* WT1 = (short*)alloc((size_t)4 * 256 * 392 * 2);
    float* x0f = (float*)alloc((size_t)BB * DD * 4);
    short* x0b = (short*)alloc((size_t)BB * DD * 2);
    float* xAf = (float*)alloc((size_t)BB * DD * 4);
    short* xAb = (short*)alloc((size_t)BB * DD * 2);
    float* xBf = (float*)alloc((size_t)BB * DD * 4);
    short* xBb = (short*)alloc((size_t)BB * DD * 2);
    short* h1b = (short*)alloc((size_t)4 * BB * HH1 * 2);

    prep_wqp<<<32, 256, 0, stream>>>(att_w1, Wqpb);
    prep_wkwp<<<32, 256, 0, stream>>>(att_w1, WkFb, WpFb);
    trans_kernel<<<dim3(601, 3), 256, 0, stream>>>(cross_W, WTc, 392, 392);
    trans_kernel<<<dim3(392, 4), 256, 0, stream>>>(exp_w1, WT1, 392, 256);
    prep_hw2<<<4, 256, 0, stream>>>(exp_w2, exp_b2, head_w, hw2, hc);

    attn_kernel<<<BB, 256, 0, stream>>>(userId, movieId, seq, dense,
                                        emb_user, emb_movie, Wqpb, WkFb, WpFb,
                                        att_b1, att_w2, att_b2,
                                        in_gamma, in_beta, x0f, x0b);

    // CrossNetV2: grid = 128 m-blocks * 7 n-blocks = 896 (%8==0)
    bgemm<2, 1, 1, 7, 1><<<896, 256, 0, stream>>>(x0b, WTc, cross_b, xAf, xAb,
                                                  x0f, x0f, BB, DD, DD, 0, 0, 0, 0);
    bgemm<2, 1, 1, 7, 1><<<896, 256, 0, stream>>>(xAb, WTc + 392 * 392, cross_b + 392,
                                                  xBf, xBb, x0f, xAf, BB, DD, DD, 0, 0, 0, 0);
    bgemm<2, 1, 0, 7, 1><<<896, 256, 0, stream>>>(xBb, WTc + 2 * 392 * 392, cross_b + 784,
                                                  xAf, nullptr, x0f, xBf, BB, DD, DD, 0, 0, 0, 0);

    // LN2: xAf -> xBf (+bf16)
    ln_kernel<<<BB, 256, 0, stream>>>(xAf, cr_gamma, cr_beta, xBf, xBb);

    // Experts layer 1: h1 = relu(x @ w1 + b1)  [E][B][256] bf16
    // grid = 128 m-blocks * 4 z * 4 n-blocks = 2048 (%8==0)
    bgemm<1, 0, 1, 4, 4><<<2048, 256, 0, stream>>>(
        xBb, WT1, exp_b1, nullptr, h1b, nullptr, nullptr,
        BB, HH1, DD, 0, (long)HH1 * DD, HH1, (long)BB * HH1);

    // gates + expert-head dots + mix -> logits [2][B]
    final_kernel<<<BB / 4, 256, 0, stream>>>(xBf, h1b, hw2, hc,
                                             gate_w, gate_b, head_b, outp);

    (void)in_sizes; (void)n_in; (void)out_size; (void)ws_size;
}

// Round 6
// 175.063 us; speedup vs baseline: 1.5281x; 1.0843x over previous
//
#include <hip/hip_runtime.h>
#include <hip/hip_bf16.h>

typedef short short8 __attribute__((ext_vector_type(8)));
typedef short short4v __attribute__((ext_vector_type(4)));
typedef float f32x4 __attribute__((ext_vector_type(4)));

constexpr int BB = 8192;   // batch
constexpr int LL = 50;     // seq len
constexpr int DE = 128;    // emb dim
constexpr int DD = 392;    // total input dim
constexpr int HH1 = 256;
constexpr int HH2 = 128;

__device__ __forceinline__ short f2b(float x) {
    __hip_bfloat16 h = __float2bfloat16(x);   // RNE
    return __builtin_bit_cast(short, h);
}
__device__ __forceinline__ float b2f(short v) {
    unsigned u = ((unsigned)(unsigned short)v) << 16;
    return __builtin_bit_cast(float, u);
}

// ---------------------------------------------------------------------------
// prep A (one launch, 68 blocks):
//  b<32 : Wq' = W1q + W1(q-k)  bf16 [128][64]
//  b<64 : Wk' / Wp in MFMA B-frag order (bf16)
//  b<68 : hw2[e][k][t] = exp_w2[e][k][:] . head_w[t][:]; hc[e][t] from bias
// ---------------------------------------------------------------------------
__global__ __launch_bounds__(256) void prep_small(
    const float* __restrict__ w1,
    const float* __restrict__ w2, const float* __restrict__ b2,
    const float* __restrict__ head_w,
    short* __restrict__ Wqpb, short* __restrict__ WkFb, short* __restrict__ WpFb,
    float* __restrict__ hw2, float* __restrict__ hc)
{
    __shared__ float hw[256];
    const int b = blockIdx.x, t = threadIdx.x;
    if (b < 32) {
        int idx = b * 256 + t;              // d*64+h
        Wqpb[idx] = f2b(w1[idx] + w1[idx + 16384]);
    } else if (b < 64) {
        int o = (b - 32) * 256 + t;         // frag-order offset
        int e = o & 7, lane = (o >> 3) & 63, nt = (o >> 9) & 3, kt = o >> 11;
        int k = (kt << 5) + ((lane >> 4) << 3) + e;
        int h = (nt << 4) + (lane & 15);
        WkFb[o] = f2b(w1[(128 + k) * 64 + h] - w1[(256 + k) * 64 + h]);
        WpFb[o] = f2b(w1[(384 + k) * 64 + h]);
    } else {
        const int e = b - 64;
        hw[t] = head_w[t];
        __syncthreads();
        const float* row = &w2[((long)e * HH1 + t) * HH2];
        float s0 = 0.f, s1 = 0.f;
        #pragma unroll 8
        for (int o = 0; o < 128; o += 4) {
            float4 v = *reinterpret_cast<const float4*>(&row[o]);
            s0 += v.x * hw[o] + v.y * hw[o + 1] + v.z * hw[o + 2] + v.w * hw[o + 3];
            s1 += v.x * hw[128 + o] + v.y * hw[129 + o] + v.z * hw[130 + o] + v.w * hw[131 + o];
        }
        hw2[(((e << 8) + t) << 1) + 0] = s0;
        hw2[(((e << 8) + t) << 1) + 1] = s1;
        if (t < 2) {
            float s = 0.f;
            for (int o = 0; o < 128; ++o) s += b2[e * 128 + o] * hw[t * 128 + o];
            hc[e * 2 + t] = s;
        }
    }
}

// ---------------------------------------------------------------------------
// prep B (one launch): WTc (cross W^T), WT1 (exp_w1^T), embB (bf16 movie table)
// ---------------------------------------------------------------------------
constexpr int S0 = 3 * 392 * 392;        // 460992
constexpr int S1 = 4 * 392 * 256;        // 401408
constexpr int S2 = (50001 * 128) / 4;    // 1600032 (4 elems each)

__global__ __launch_bounds__(256) void prep_trans(
    const float* __restrict__ cross_W, const float* __restrict__ exp_w1,
    const float* __restrict__ emb_movie,
    short* __restrict__ WTc, short* __restrict__ WT1, short* __restrict__ embB)
{
    int idx = blockIdx.x * 256 + threadIdx.x;
    if (idx < S0) {
        int z = idx / (392 * 392), rr = idx - z * 392 * 392;
        int c = rr / 392, r = rr - c * 392;
        WTc[idx] = f2b(cross_W[(long)z * 153664 + r * 392 + c]);
    } else if (idx < S0 + S1) {
        int j = idx - S0;
        int z = j / 100352, rr = j - z * 100352;
        int c = rr / 392, r = rr - c * 392;
        WT1[j] = f2b(exp_w1[(long)z * 100352 + r * 256 + c]);
    } else if (idx < S0 + S1 + S2) {
        long j = (long)(idx - S0 - S1) << 2;
        float4 v = *reinterpret_cast<const float4*>(&emb_movie[j]);
        short4v o;
        o[0] = f2b(v.x); o[1] = f2b(v.y); o[2] = f2b(v.z); o[3] = f2b(v.w);
        *reinterpret_cast<short4v*>(&embB[j]) = o;
    }
}

// ---------------------------------------------------------------------------
// K1: DIN attention (MFMA, q folded into B) + concat + LayerNorm1 -> x0
// hist staged from bf16 table (branchless; row 0 is zeros) into swizzled LDS.
// ---------------------------------------------------------------------------
__global__ __launch_bounds__(256, 8) void attn_kernel(
    const int* __restrict__ userId, const int* __restrict__ movieId,
    const int* __restrict__ seq, const float* __restrict__ dense,
    const float* __restrict__ emb_user, const float* __restrict__ emb_movie,
    const short* __restrict__ embB,
    const short* __restrict__ Wqpb, const short* __restrict__ WkFb,
    const short* __restrict__ WpFb,
    const float* __restrict__ att_b1, const float* __restrict__ att_w2,
    const float* __restrict__ att_b2,
    const float* __restrict__ in_gamma, const float* __restrict__ in_beta,
    float* __restrict__ x0f, short* __restrict__ x0b)
{
    __shared__ short hist[64 * 128];    // swizzled: byte = l*256 + (bytecol ^ ((l&7)<<4))
    __shared__ float qs[128];
    __shared__ int   seq_s[64];
    __shared__ float qconst[64];
    __shared__ float sp[4][64];
    __shared__ float probs[64];
    __shared__ float xrow[392];
    __shared__ float stats[2];

    const int b = blockIdx.x;
    const int t = threadIdx.x;
    const int lane = t & 63;
    const int w = t >> 6;

    if (t < 128) qs[t] = emb_movie[(long)movieId[b] * DE + t];
    if (t < 64)  seq_s[t] = (t < LL) ? seq[b * LL + t] : 0;
    __syncthreads();   // A

    // stage hist bf16 swizzled, branchless (seq_s[l>=LL]=0 -> zero row)
    #pragma unroll
    for (int i = 0; i < 4; ++i) {
        const int idx = t + (i << 8);
        const int l = idx >> 4, c = idx & 15;
        short8 hv = *reinterpret_cast<const short8*>(&embB[(long)seq_s[l] * DE + (c << 3)]);
        const int byte = (l << 8) + ((c << 4) ^ ((l & 7) << 4));
        *reinterpret_cast<short8*>(reinterpret_cast<char*>(hist) + byte) = hv;
    }

    // hoisted independent gathers
    float ue = (t < 128) ? emb_user[(long)userId[b] * DE + t] : 0.f;
    float dv = (t < 8) ? dense[b * 8 + t] : 0.f;

    // per-row B fragments: V[k][h] = Wk'[k][h] + q[k]*Wp[k][h]
    short8 bfrag[4];
    #pragma unroll
    for (int kt = 0; kt < 4; ++kt) {
        const int fo = ((((kt << 2) + w) << 6) | lane) << 3;
        short8 wk = *reinterpret_cast<const short8*>(&WkFb[fo]);
        short8 wp = *reinterpret_cast<const short8*>(&WpFb[fo]);
        const int kq = (kt << 5) + ((lane >> 4) << 3);
        #pragma unroll
        for (int j = 0; j < 8; ++j)
            bfrag[kt][j] = f2b(fmaf(qs[kq + j], b2f(wp[j]), b2f(wk[j])));
    }

    // qconst partial: wave w covers d in [32w, 32w+32)
    {
        float s = 0.f;
        const int dq = w << 5;
        #pragma unroll
        for (int dd = 0; dd < 32; ++dd)
            s = fmaf(qs[dq + dd], b2f(Wqpb[(dq + dd) * 64 + lane]), s);
        sp[w][lane] = s;
    }
    __syncthreads();   // B
    if (t < 64) qconst[t] = att_b1[t] + sp[0][t] + sp[1][t] + sp[2][t] + sp[3][t];
    __syncthreads();   // C

    // MFMA per m-tile, immediately reduced to score partials
    {
        const float qc  = qconst[(w << 4) + (lane & 15)];
        const float w2v = att_w2[(w << 4) + (lane & 15)];
        #pragma unroll
        for (int mt = 0; mt < 4; ++mt) {
            f32x4 acc;
            #pragma unroll
            for (int r = 0; r < 4; ++r) acc[r] = qc;
            const int row = (mt << 4) + (lane & 15);
            const int rbase = row << 8;
            const int swz = (row & 7) << 4;
            #pragma unroll
            for (int kt = 0; kt < 4; ++kt) {
                const int kbyte = (kt << 6) + ((lane >> 4) << 4);
                short8 a = *reinterpret_cast<const short8*>(
                    reinterpret_cast<char*>(hist) + rbase + (kbyte ^ swz));
                acc = __builtin_amdgcn_mfma_f32_16x16x32_bf16(a, bfrag[kt], acc, 0, 0, 0);
            }
            #pragma unroll
            for (int r = 0; r < 4; ++r) {
                float v = fmaxf(acc[r], 0.f) * w2v;
                v += __shfl_xor(v, 1); v += __shfl_xor(v, 2);
                v += __shfl_xor(v, 4); v += __shfl_xor(v, 8);
                if ((lane & 15) == 0)
                    sp[w][(mt << 4) + ((lane >> 4) << 2) + r] = v;
            }
        }
    }
    __syncthreads();   // D

    // masked softmax over l (threads 0..63); probs[l>=LL] = 0
    if (t < 64) {
        float sc = sp[0][t] + sp[1][t] + sp[2][t] + sp[3][t] + att_b2[0];
        float s = (t < LL) ? ((seq_s[t] > 0) ? sc : -1e9f) : -INFINITY;
        float m = s;
        #pragma unroll
        for (int off = 32; off > 0; off >>= 1) m = fmaxf(m, __shfl_xor(m, off));
        float e = (t < LL) ? __expf(s - m) : 0.f;
        float sum = e;
        #pragma unroll
        for (int off = 32; off > 0; off >>= 1) sum += __shfl_xor(sum, off);
        probs[t] = (t < LL) ? (e / sum) : 0.f;
    }
    __syncthreads();   // E

    // interest partials from the LDS bf16 hist
    const int g  = t >> 5;
    const int d0 = (t & 31) << 2;
    float4 ps = make_float4(0.f, 0.f, 0.f, 0.f);
    #pragma unroll
    for (int i = 0; i < 8; ++i) {
        const int l = g + (i << 3);
        const int byte = (l << 8) + ((d0 << 1) ^ ((l & 7) << 4));
        short4v hv = *reinterpret_cast<const short4v*>(
            reinterpret_cast<const char*>(hist) + byte);
        const float p = probs[l];
        ps.x = fmaf(p, b2f(hv[0]), ps.x);
        ps.y = fmaf(p, b2f(hv[1]), ps.y);
        ps.z = fmaf(p, b2f(hv[2]), ps.z);
        ps.w = fmaf(p, b2f(hv[3]), ps.w);
    }
    ps.x += __shfl_xor(ps.x, 32); ps.y += __shfl_xor(ps.y, 32);
    ps.z += __shfl_xor(ps.z, 32); ps.w += __shfl_xor(ps.w, 32);
    __syncthreads();   // F1: all hist reads done, safe to reuse as scratch
    float* scr = reinterpret_cast<float*>(hist);   // [4][128] f32
    if (lane < 32)
        *reinterpret_cast<float4*>(&scr[(w << 7) + ((lane & 31) << 2)]) = ps;
    __syncthreads();   // F2
    if (t < 128) {
        xrow[256 + t] = scr[t] + scr[128 + t] + scr[256 + t] + scr[384 + t];
        xrow[t] = ue;
        xrow[128 + t] = qs[t];
        if (t < 8) xrow[384 + t] = dv;
    }
    __syncthreads();   // G

    // LayerNorm over 392
    float v0 = xrow[t];
    float v1 = (t < 136) ? xrow[256 + t] : 0.f;
    float s2 = v0 + v1, q2 = v0 * v0 + v1 * v1;
    #pragma unroll
    for (int off = 32; off > 0; off >>= 1) {
        s2 += __shfl_xor(s2, off);
        q2 += __shfl_xor(q2, off);
    }
    if (lane == 0) { sp[0][w] = s2; sp[1][w] = q2; }
    __syncthreads();
    if (t == 0) {
        float S = sp[0][0] + sp[0][1] + sp[0][2] + sp[0][3];
        float Q = sp[1][0] + sp[1][1] + sp[1][2] + sp[1][3];
        float mean = S / (float)DD;
        float var = Q / (float)DD - mean * mean;
        stats[0] = mean;
        stats[1] = rsqrtf(var + 1e-5f);
    }
    __syncthreads();
    const float mean = stats[0], inv = stats[1];
    const long base = (long)b * DD;
    float o0 = (v0 - mean) * inv * in_gamma[t] + in_beta[t];
    x0f[base + t] = o0; x0b[base + t] = f2b(o0);
    if (t < 136) {
        float o1 = (v1 - mean) * inv * in_gamma[256 + t] + in_beta[256 + t];
        x0f[base + 256 + t] = o1; x0b[base + 256 + t] = f2b(o1);
    }
}

// ---------------------------------------------------------------------------
// bf16 MFMA GEMM, 2-phase double-buffered pipeline + chunked-XCD swizzle.
// out = f(A[M,K](bf16) @ WT[N,K]^T(bf16) + bias)
// MODE 0: +bias ; 1: relu(+bias) ; 2: cross: out = x0*(acc+bias)+xin
// 1-D grid, id m-major: id = mb*(NXB*NZB) + z*NXB + xb. grid%8 must be 0.
// ---------------------------------------------------------------------------
template<int MODE, int WF32, int WB16, int NXB, int NZB>
__global__ __launch_bounds__(256) void bgemm(
    const short* __restrict__ A, const short* __restrict__ WT,
    const float* __restrict__ bias,
    float* __restrict__ outF, short* __restrict__ outB,
    const float* __restrict__ x0, const float* __restrict__ xin,
    int M, int N, int K, long aZ, long wZ, long bZ, long oZ)
{
    __shared__ short As[2][64 * 64];   // swizzled: byte = r*128 + ((k*2)^((r&7)<<4))
    __shared__ short Bs[2][64 * 64];

    int id = blockIdx.x;
    const int qq = (int)gridDim.x >> 3;
    id = (id & 7) * qq + (id >> 3);
    const int mb  = id / (NXB * NZB);
    const int rem = id - mb * (NXB * NZB);
    const int z   = rem / NXB;
    const int xb  = rem - z * NXB;

    A += (long)z * aZ; WT += (long)z * wZ; bias += (long)z * bZ;
    const long oz = (long)z * oZ;

    const int t = threadIdx.x, w = t >> 6, lane = t & 63;
    const int m0 = mb * 64, n0 = xb * 64;
    const int sm = t >> 3, sk8 = (t & 7) << 3;

    f32x4 acc[4];
    #pragma unroll
    for (int i = 0; i < 4; ++i) {
        #pragma unroll
        for (int r = 0; r < 4; ++r) acc[i][r] = 0.f;
    }

    const int nsteps = (K + 63) >> 6;
    short8 avr[2], bvr[2];

    auto loadr = [&](int k0) {
        #pragma unroll
        for (int i = 0; i < 2; ++i) {
            const int r = sm + (i << 5);
            short8 zv = {0, 0, 0, 0, 0, 0, 0, 0};
            avr[i] = zv; bvr[i] = zv;
            if (k0 + sk8 < K) {
                avr[i] = *reinterpret_cast<const short8*>(&A[(long)(m0 + r) * K + k0 + sk8]);
                if (n0 + r < N)
                    bvr[i] = *reinterpret_cast<const short8*>(&WT[(long)(n0 + r) * K + k0 + sk8]);
            }
        }
    };
    auto writelds = [&](int buf) {
        #pragma unroll
        for (int i = 0; i < 2; ++i) {
            const int r = sm + (i << 5);
            const int byte = (r << 7) + ((sk8 << 1) ^ ((r & 7) << 4));
            *reinterpret_cast<short8*>(reinterpret_cast<char*>(&As[buf][0]) + byte) = avr[i];
            *reinterpret_cast<short8*>(reinterpret_cast<char*>(&Bs[buf][0]) + byte) = bvr[i];
        }
    };

    loadr(0);
    writelds(0);
    __syncthreads();

    int cur = 0;
    for (int s = 0; s < nsteps; ++s) {
        if (s + 1 < nsteps) loadr((s + 1) << 6);
        #pragma unroll
        for (int kt = 0; kt < 2; ++kt) {
            const int kbyte = (kt << 6) + ((lane >> 4) << 4);
            const int ar = (w << 4) + (lane & 15);
            short8 a = *reinterpret_cast<const short8*>(
                reinterpret_cast<char*>(&As[cur][0]) + (ar << 7) + (kbyte ^ ((ar & 7) << 4)));
            #pragma unroll
            for (int nt = 0; nt < 4; ++nt) {
                const int br = (nt << 4) + (lane & 15);
                short8 bb = *reinterpret_cast<const short8*>(
                    reinterpret_cast<char*>(&Bs[cur][0]) + (br << 7) + (kbyte ^ ((br & 7) << 4)));
                acc[nt] = __builtin_amdgcn_mfma_f32_16x16x32_bf16(a, bb, acc[nt], 0, 0, 0);
            }
        }
        if (s + 1 < nsteps) writelds(cur ^ 1);
        __syncthreads();
        cur ^= 1;
    }

    #pragma unroll
    for (int nt = 0; nt < 4; ++nt) {
        const int col = n0 + (nt << 4) + (lane & 15);
        if (col < N) {
            const float bv = bias[col];
            #pragma unroll
            for (int r = 0; r < 4; ++r) {
                const int row = m0 + (w << 4) + ((lane >> 4) << 2) + r;
                float v = acc[nt][r] + bv;
                if (MODE == 1) v = fmaxf(v, 0.f);
                const long o = (long)row * N + col;
                if (MODE == 2) v = x0[o] * v + xin[o];
                if (WF32) outF[oz + o] = v;
                if (WB16) outB[oz + o] = f2b(v);
            }
        }
    }
}

// ---------------------------------------------------------------------------
// LayerNorm over 392 (block per row), f32 + bf16 outputs
// ---------------------------------------------------------------------------
__global__ __launch_bounds__(256) void ln_kernel(
    const float* __restrict__ in,
    const float* __restrict__ gamma, const float* __restrict__ beta,
    float* __restrict__ outF, short* __restrict__ outB)
{
    __shared__ float red[2][4];
    __shared__ float stats[2];
    const int b = blockIdx.x, t = threadIdx.x, lane = t & 63, w = t >> 6;
    const long base = (long)b * DD;
    float v0 = in[base + t];
    float v1 = (t < 136) ? in[base + 256 + t] : 0.f;
    float s = v0 + v1, q2 = v0 * v0 + v1 * v1;
    #pragma unroll
    for (int off = 32; off > 0; off >>= 1) {
        s += __shfl_xor(s, off);
        q2 += __shfl_xor(q2, off);
    }
    if (lane == 0) { red[0][w] = s; red[1][w] = q2; }
    __syncthreads();
    if (t == 0) {
        float S = red[0][0] + red[0][1] + red[0][2] + red[0][3];
        float Q = red[1][0] + red[1][1] + red[1][2] + red[1][3];
        float mean = S / (float)DD;
        float var = Q / (float)DD - mean * mean;
        stats[0] = mean;
        stats[1] = rsqrtf(var + 1e-5f);
    }
    __syncthreads();
    const float mean = stats[0], inv = stats[1];
    float o0 = (v0 - mean) * inv * gamma[t] + beta[t];
    outF[base + t] = o0; outB[base + t] = f2b(o0);
    if (t < 136) {
        float o1 = (v1 - mean) * inv * gamma[256 + t] + beta[256 + t];
        outF[base + 256 + t] = o1; outB[base + 256 + t] = f2b(o1);
    }
}

// ---------------------------------------------------------------------------
// K3: gates (from x f32) + expert-head dots (from h1 bf16 via hw2) + mix.
// ---------------------------------------------------------------------------
__global__ __launch_bounds__(256) void final_kernel(
    const float* __restrict__ x, const short* __restrict__ h1,
    const float* __restrict__ hw2, const float* __restrict__ hc,
    const float* __restrict__ gate_w, const float* __restrict__ gate_b,
    const float* __restrict__ head_b, float* __restrict__ out)
{
    const int t = threadIdx.x, lane = t & 63, w = t >> 6;
    const int b = blockIdx.x * 4 + w;
    const float* xr = x + (long)b * DD;

    float xv[7];
    #pragma unroll
    for (int i = 0; i < 7; ++i) {
        int d = lane + (i << 6);
        xv[i] = (d < DD) ? xr[d] : 0.f;
    }

    float gl[8] = {0.f, 0.f, 0.f, 0.f, 0.f, 0.f, 0.f, 0.f};
    #pragma unroll
    for (int i = 0; i < 7; ++i) {
        int d = lane + (i << 6);
        if (d < DD) {
            float4 g0 = *reinterpret_cast<const float4*>(&gate_w[d << 2]);
            float4 g1 = *reinterpret_cast<const float4*>(&gate_w[1568 + (d << 2)]);
            gl[0] = fmaf(xv[i], g0.x, gl[0]); gl[1] = fmaf(xv[i], g0.y, gl[1]);
            gl[2] = fmaf(xv[i], g0.z, gl[2]); gl[3] = fmaf(xv[i], g0.w, gl[3]);
            gl[4] = fmaf(xv[i], g1.x, gl[4]); gl[5] = fmaf(xv[i], g1.y, gl[5]);
            gl[6] = fmaf(xv[i], g1.z, gl[6]); gl[7] = fmaf(xv[i], g1.w, gl[7]);
        }
    }

    float ed[8];
    #pragma unroll
    for (int e = 0; e < 4; ++e) {
        short4v hv = *reinterpret_cast<const short4v*>(
            &h1[((long)e * BB + b) * HH1 + (lane << 2)]);
        const float* hwp = &hw2[(((e << 8) + (lane << 2))) << 1];
        float4 w01 = *reinterpret_cast<const float4*>(hwp);
        float4 w23 = *reinterpret_cast<const float4*>(hwp + 4);
        float h0 = b2f(hv[0]), h1f = b2f(hv[1]), h2 = b2f(hv[2]), h3 = b2f(hv[3]);
        ed[e]     = fmaf(h0, w01.x, fmaf(h1f, w01.z, fmaf(h2, w23.x, h3 * w23.z)));
        ed[4 + e] = fmaf(h0, w01.y, fmaf(h1f, w01.w, fmaf(h2, w23.y, h3 * w23.w)));
    }

    #pragma unroll
    for (int v = 0; v < 8; ++v) {
        #pragma unroll
        for (int off = 32; off > 0; off >>= 1) {
            gl[v] += __shfl_xor(gl[v], off);
            ed[v] += __shfl_xor(ed[v], off);
        }
    }

    if (lane == 0) {
        float res[2];
        #pragma unroll
        for (int tt = 0; tt < 2; ++tt) {
            float lv[4], m = -1e30f;
            #pragma unroll
            for (int e = 0; e < 4; ++e) {
                lv[e] = gl[tt * 4 + e] + gate_b[tt * 4 + e];
                m = fmaxf(m, lv[e]);
            }
            float sum = 0.f, acc = 0.f;
            #pragma unroll
            for (int e = 0; e < 4; ++e) { lv[e] = __expf(lv[e] - m); sum += lv[e]; }
            #pragma unroll
            for (int e = 0; e < 4; ++e)
                acc = fmaf(lv[e], ed[tt * 4 + e] + hc[e * 2 + tt], acc);
            res[tt] = head_b[tt] + acc / sum;
        }
        out[b] = res[0];
        out[BB + b] = res[1];
    }
}

// ---------------------------------------------------------------------------
extern "C" void kernel_launch(void* const* d_in, const int* in_sizes, int n_in,
                              void* d_out, int out_size, void* d_ws, size_t ws_size,
                              hipStream_t stream) {
    const int*   userId    = (const int*)d_in[0];
    const int*   movieId   = (const int*)d_in[1];
    const int*   seq       = (const int*)d_in[2];
    const float* dense     = (const float*)d_in[3];
    const float* emb_user  = (const float*)d_in[4];
    const float* emb_movie = (const float*)d_in[5];
    const float* att_w1    = (const float*)d_in[6];
    const float* att_b1    = (const float*)d_in[7];
    const float* att_w2    = (const float*)d_in[8];
    const float* att_b2    = (const float*)d_in[9];
    const float* in_gamma  = (const float*)d_in[10];
    const float* in_beta   = (const float*)d_in[11];
    const float* cr_gamma  = (const float*)d_in[12];
    const float* cr_beta   = (const float*)d_in[13];
    const float* cross_W   = (const float*)d_in[14];
    const float* cross_b   = (const float*)d_in[15];
    const float* exp_w1    = (const float*)d_in[16];
    const float* exp_b1    = (const float*)d_in[17];
    const float* exp_w2    = (const float*)d_in[18];
    const float* exp_b2    = (const float*)d_in[19];
    const float* gate_w    = (const float*)d_in[20];
    const float* gate_b    = (const float*)d_in[21];
    const float* head_w    = (const float*)d_in[22];
    const float* head_b    = (const float*)d_in[23];
    float* outp = (float*)d_out;

    char* p = (char*)d_ws;
    auto alloc = [&](size_t bytes) -> char* {
        char* r = p; p += (bytes + 255) & ~(size_t)255; return r;
    };
    short* Wqpb = (short*)alloc(8192 * 2);
    short* WkFb = (short*)alloc(8192 * 2);
    short* WpFb = (short*)alloc(8192 * 2);
    float* hw2 = (float*)alloc(2048 * 4);
    float* hc  = (float*)alloc(8 * 4);
    short* WTc = (short*)alloc((size_t)3 * 392 * 392 * 2);
    short* WT1 = (short*)alloc((size_t)4 * 256 * 392 * 2);
    short* embB = (short*)alloc((size_t)50001 * 128 * 2);
    float* x0f = (float*)alloc((size_t)BB * DD * 4);
    short* x0b = (short*)alloc((size_t)BB * DD * 2);
    float* xAf = (float*)alloc((size_t)BB * DD * 4);
    short* xAb = (short*)alloc((size_t)BB * DD * 2);
    float* xBf = (float*)alloc((size_t)BB * DD * 4);
    short* xBb = (short*)alloc((size_t)BB * DD * 2);
    short* h1b = (short*)alloc((size_t)4 * BB * HH1 * 2);

    prep_small<<<68, 256, 0, stream>>>(att_w1, exp_w2, exp_b2, head_w,
                                       Wqpb, WkFb, WpFb, hw2, hc);
    prep_trans<<<(S0 + S1 + S2 + 255) / 256, 256, 0, stream>>>(
        cross_W, exp_w1, emb_movie, WTc, WT1, embB);

    attn_kernel<<<BB, 256, 0, stream>>>(userId, movieId, seq, dense,
                                        emb_user, emb_movie, embB,
                                        Wqpb, WkFb, WpFb,
                                        att_b1, att_w2, att_b2,
                                        in_gamma, in_beta, x0f, x0b);

    // CrossNetV2: grid = 128 m-blocks * 7 n-blocks = 896 (%8==0)
    bgemm<2, 1, 1, 7, 1><<<896, 256, 0, stream>>>(x0b, WTc, cross_b, xAf, xAb,
                                                  x0f, x0f, BB, DD, DD, 0, 0, 0, 0);
    bgemm<2, 1, 1, 7, 1><<<896, 256, 0, stream>>>(xAb, WTc + 392 * 392, cross_b + 392,
                                                  xBf, xBb, x0f, xAf, BB, DD, DD, 0, 0, 0, 0);
    bgemm<2, 1, 0, 7, 1><<<896, 256, 0, stream>>>(xBb, WTc + 2 * 392 * 392, cross_b + 784,
                                                  xAf, nullptr, x0f, xBf, BB, DD, DD, 0, 0, 0, 0);

    // LN2: xAf -> xBf (+bf16)
    ln_kernel<<<BB, 256, 0, stream>>>(xAf, cr_gamma, cr_beta, xBf, xBb);

    // Experts layer 1: h1 = relu(x @ w1 + b1)  [E][B][256] bf16
    bgemm<1, 0, 1, 4, 4><<<2048, 256, 0, stream>>>(
        xBb, WT1, exp_b1, nullptr, h1b, nullptr, nullptr,
        BB, HH1, DD, 0, (long)HH1 * DD, HH1, (long)BB * HH1);

    // gates + expert-head dots + mix -> logits [2][B]
    final_kernel<<<BB / 4, 256, 0, stream>>>(xBf, h1b, hw2, hc,
                                             gate_w, gate_b, head_b, outp);

    (void)in_sizes; (void)n_in; (void)out_size; (void)ws_size;
}

// Round 7
// 174.279 us; speedup vs baseline: 1.5350x; 1.0045x over previous
//
#include <hip/hip_runtime.h>
#include <hip/hip_bf16.h>

typedef short short8 __attribute__((ext_vector_type(8)));
typedef short short4v __attribute__((ext_vector_type(4)));
typedef float f32x4 __attribute__((ext_vector_type(4)));

constexpr int BB = 8192;   // batch
constexpr int LL = 50;     // seq len
constexpr int DE = 128;    // emb dim
constexpr int DD = 392;    // total input dim
constexpr int HH1 = 256;
constexpr int HH2 = 128;

__device__ __forceinline__ short f2b(float x) {
    __hip_bfloat16 h = __float2bfloat16(x);   // RNE
    return __builtin_bit_cast(short, h);
}
__device__ __forceinline__ float b2f(short v) {
    unsigned u = ((unsigned)(unsigned short)v) << 16;
    return __builtin_bit_cast(float, u);
}

// ---------------------------------------------------------------------------
// prep A (one launch, 68 blocks):
//  b<32 : WqpT[h][d] = bf16(W1q + W1(q-k))  transposed [64][128]
//  b<64 : WkpF interleaved frag table: [kt][nt][lane][ wk(8) | wp(8) ]
//  b<68 : hw2[e][k][t] = exp_w2[e][k][:] . head_w[t][:]; hc[e][t] from bias
// ---------------------------------------------------------------------------
__global__ __launch_bounds__(256) void prep_small(
    const float* __restrict__ w1,
    const float* __restrict__ w2, const float* __restrict__ b2,
    const float* __restrict__ head_w,
    short* __restrict__ WqpT, short* __restrict__ WkpF,
    float* __restrict__ hw2, float* __restrict__ hc)
{
    __shared__ float hw[256];
    const int b = blockIdx.x, t = threadIdx.x;
    if (b < 32) {
        int o = b * 256 + t;                // h*128 + d
        int h = o >> 7, d = o & 127;
        WqpT[o] = f2b(w1[d * 64 + h] + w1[16384 + d * 64 + h]);
    } else if (b < 64) {
        int o = (b - 32) * 256 + t;         // [kt][nt][lane][e] index, 8192
        int e = o & 7, lane = (o >> 3) & 63, nt = (o >> 9) & 3, kt = o >> 11;
        int k = (kt << 5) + ((lane >> 4) << 3) + e;
        int h = (nt << 4) + (lane & 15);
        int base = (o >> 3) << 4;
        WkpF[base + e]     = f2b(w1[(128 + k) * 64 + h] - w1[(256 + k) * 64 + h]);
        WkpF[base + 8 + e] = f2b(w1[(384 + k) * 64 + h]);
    } else {
        const int e = b - 64;
        hw[t] = head_w[t];
        __syncthreads();
        const float* row = &w2[((long)e * HH1 + t) * HH2];
        float s0 = 0.f, s1 = 0.f;
        #pragma unroll 8
        for (int o = 0; o < 128; o += 4) {
            float4 v = *reinterpret_cast<const float4*>(&row[o]);
            s0 += v.x * hw[o] + v.y * hw[o + 1] + v.z * hw[o + 2] + v.w * hw[o + 3];
            s1 += v.x * hw[128 + o] + v.y * hw[129 + o] + v.z * hw[130 + o] + v.w * hw[131 + o];
        }
        hw2[(((e << 8) + t) << 1) + 0] = s0;
        hw2[(((e << 8) + t) << 1) + 1] = s1;
        if (t < 2) {
            float s = 0.f;
            for (int o = 0; o < 128; ++o) s += b2[e * 128 + o] * hw[t * 128 + o];
            hc[e * 2 + t] = s;
        }
    }
}

// ---------------------------------------------------------------------------
// prep B (one launch): WTc (cross W^T), WT1 (exp_w1^T), embB (bf16 movie table)
// ---------------------------------------------------------------------------
constexpr int S0 = 3 * 392 * 392;        // 460992
constexpr int S1 = 4 * 392 * 256;        // 401408
constexpr int S2 = (50001 * 128) / 4;    // 1600032 (4 elems each)

__global__ __launch_bounds__(256) void prep_trans(
    const float* __restrict__ cross_W, const float* __restrict__ exp_w1,
    const float* __restrict__ emb_movie,
    short* __restrict__ WTc, short* __restrict__ WT1, short* __restrict__ embB)
{
    int idx = blockIdx.x * 256 + threadIdx.x;
    if (idx < S0) {
        int z = idx / (392 * 392), rr = idx - z * 392 * 392;
        int c = rr / 392, r = rr - c * 392;
        WTc[idx] = f2b(cross_W[(long)z * 153664 + r * 392 + c]);
    } else if (idx < S0 + S1) {
        int j = idx - S0;
        int z = j / 100352, rr = j - z * 100352;
        int c = rr / 392, r = rr - c * 392;
        WT1[j] = f2b(exp_w1[(long)z * 100352 + r * 256 + c]);
    } else if (idx < S0 + S1 + S2) {
        long j = (long)(idx - S0 - S1) << 2;
        float4 v = *reinterpret_cast<const float4*>(&emb_movie[j]);
        short4v o;
        o[0] = f2b(v.x); o[1] = f2b(v.y); o[2] = f2b(v.z); o[3] = f2b(v.w);
        *reinterpret_cast<short4v*>(&embB[j]) = o;
    }
}

// ---------------------------------------------------------------------------
// K1: DIN attention (MFMA, q folded into B) + concat + LayerNorm1 -> x0
// 7-barrier schedule; qconst folded post-MFMA; no xrow staging.
// ---------------------------------------------------------------------------
__global__ __launch_bounds__(256, 8) void attn_kernel(
    const int* __restrict__ userId, const int* __restrict__ movieId,
    const int* __restrict__ seq, const float* __restrict__ dense,
    const float* __restrict__ emb_user, const float* __restrict__ emb_movie,
    const short* __restrict__ embB,
    const short* __restrict__ WqpT, const short* __restrict__ WkpF,
    const float* __restrict__ att_b1, const float* __restrict__ att_w2,
    const float* __restrict__ att_b2,
    const float* __restrict__ in_gamma, const float* __restrict__ in_beta,
    float* __restrict__ x0f, short* __restrict__ x0b)
{
    __shared__ short hist[64 * 128];    // swizzled: byte = l*256 + (bytecol ^ ((l&7)<<4))
    __shared__ float qs[128];
    __shared__ int   seq_s[64];
    __shared__ float sp[4][64];         // qconst partials, later LN partials
    __shared__ float spS[4][64];        // score partials
    __shared__ float probs[64];
    __shared__ float ibuf[4][128];      // interest partials
    __shared__ float stats[2];

    const int b = blockIdx.x;
    const int t = threadIdx.x;
    const int lane = t & 63;
    const int w = t >> 6;

    if (t < 128) qs[t] = emb_movie[(long)movieId[b] * DE + t];
    if (t < 64)  seq_s[t] = (t < LL) ? seq[b * LL + t] : 0;
    __syncthreads();   // A

    // stage hist bf16 swizzled, branchless (seq_s[l>=LL]=0 -> zero row)
    #pragma unroll
    for (int i = 0; i < 4; ++i) {
        const int idx = t + (i << 8);
        const int l = idx >> 4, c = idx & 15;
        short8 hv = *reinterpret_cast<const short8*>(&embB[(long)seq_s[l] * DE + (c << 3)]);
        const int byte = (l << 8) + ((c << 4) ^ ((l & 7) << 4));
        *reinterpret_cast<short8*>(reinterpret_cast<char*>(hist) + byte) = hv;
    }

    // hoisted independent gathers
    float ue = (t < 128) ? emb_user[(long)userId[b] * DE + t] : 0.f;
    float dv = (t >= 128 && t < 136) ? dense[b * 8 + (t - 128)] : 0.f;

    // per-row B fragments: V[k][h] = Wk'[k][h] + q[k]*Wp[k][h]
    short8 bfrag[4];
    #pragma unroll
    for (int kt = 0; kt < 4; ++kt) {
        const int fo = ((((kt << 2) + w) << 6) | lane) << 4;
        short8 wk = *reinterpret_cast<const short8*>(&WkpF[fo]);
        short8 wp = *reinterpret_cast<const short8*>(&WkpF[fo + 8]);
        const int kq = (kt << 5) + ((lane >> 4) << 3);
        #pragma unroll
        for (int j = 0; j < 8; ++j)
            bfrag[kt][j] = f2b(fmaf(qs[kq + j], b2f(wp[j]), b2f(wk[j])));
    }

    // qconst partial: thread handles h=lane, d in [32w, 32w+32) (vectorized)
    {
        float s = 0.f;
        const short* wq = &WqpT[(lane << 7) + (w << 5)];
        #pragma unroll
        for (int c = 0; c < 4; ++c) {
            short8 wv = *reinterpret_cast<const short8*>(&wq[c << 3]);
            #pragma unroll
            for (int j = 0; j < 8; ++j)
                s = fmaf(qs[(w << 5) + (c << 3) + j], b2f(wv[j]), s);
        }
        sp[w][lane] = s;
    }
    __syncthreads();   // B (hist + qconst partials ready)

    // MFMA per m-tile, qconst added post-MFMA, reduce to score partials
    {
        const int col = (w << 4) + (lane & 15);
        const float qc = att_b1[col] + sp[0][col] + sp[1][col] + sp[2][col] + sp[3][col];
        const float w2v = att_w2[col];
        #pragma unroll
        for (int mt = 0; mt < 4; ++mt) {
            f32x4 acc = {0.f, 0.f, 0.f, 0.f};
            const int row = (mt << 4) + (lane & 15);
            const int rbase = row << 8;
            const int swz = (row & 7) << 4;
            #pragma unroll
            for (int kt = 0; kt < 4; ++kt) {
                const int kbyte = (kt << 6) + ((lane >> 4) << 4);
                short8 a = *reinterpret_cast<const short8*>(
                    reinterpret_cast<char*>(hist) + rbase + (kbyte ^ swz));
                acc = __builtin_amdgcn_mfma_f32_16x16x32_bf16(a, bfrag[kt], acc, 0, 0, 0);
            }
            #pragma unroll
            for (int r = 0; r < 4; ++r) {
                float v = fmaxf(acc[r] + qc, 0.f) * w2v;
                v += __shfl_xor(v, 1); v += __shfl_xor(v, 2);
                v += __shfl_xor(v, 4); v += __shfl_xor(v, 8);
                if ((lane & 15) == 0)
                    spS[w][(mt << 4) + ((lane >> 4) << 2) + r] = v;
            }
        }
    }
    __syncthreads();   // C

    // masked softmax over l (threads 0..63); probs[l>=LL] = 0
    if (t < 64) {
        float sc = spS[0][t] + spS[1][t] + spS[2][t] + spS[3][t] + att_b2[0];
        float s = (t < LL) ? ((seq_s[t] > 0) ? sc : -1e9f) : -INFINITY;
        float m = s;
        #pragma unroll
        for (int off = 32; off > 0; off >>= 1) m = fmaxf(m, __shfl_xor(m, off));
        float e = (t < LL) ? __expf(s - m) : 0.f;
        float sum = e;
        #pragma unroll
        for (int off = 32; off > 0; off >>= 1) sum += __shfl_xor(sum, off);
        probs[t] = (t < LL) ? (e / sum) : 0.f;
    }
    __syncthreads();   // D

    // interest partials from the LDS bf16 hist
    const int g  = t >> 5;
    const int d0 = (t & 31) << 2;
    float4 ps = make_float4(0.f, 0.f, 0.f, 0.f);
    #pragma unroll
    for (int i = 0; i < 8; ++i) {
        const int l = g + (i << 3);
        const int byte = (l << 8) + ((d0 << 1) ^ ((l & 7) << 4));
        short4v hv = *reinterpret_cast<const short4v*>(
            reinterpret_cast<const char*>(hist) + byte);
        const float p = probs[l];
        ps.x = fmaf(p, b2f(hv[0]), ps.x);
        ps.y = fmaf(p, b2f(hv[1]), ps.y);
        ps.z = fmaf(p, b2f(hv[2]), ps.z);
        ps.w = fmaf(p, b2f(hv[3]), ps.w);
    }
    ps.x += __shfl_xor(ps.x, 32); ps.y += __shfl_xor(ps.y, 32);
    ps.z += __shfl_xor(ps.z, 32); ps.w += __shfl_xor(ps.w, 32);
    if (lane < 32)
        *reinterpret_cast<float4*>(&ibuf[w][lane << 2]) = ps;
    __syncthreads();   // E

    // LN inputs directly in registers (no xrow staging)
    float v0 = (t < 128) ? ue : qs[t - 128];
    float v1 = 0.f;
    if (t < 128)       v1 = ibuf[0][t] + ibuf[1][t] + ibuf[2][t] + ibuf[3][t];
    else if (t < 136)  v1 = dv;

    float s2 = v0 + v1, q2 = v0 * v0 + v1 * v1;
    #pragma unroll
    for (int off = 32; off > 0; off >>= 1) {
        s2 += __shfl_xor(s2, off);
        q2 += __shfl_xor(q2, off);
    }
    if (lane == 0) { sp[0][w] = s2; sp[1][w] = q2; }
    __syncthreads();   // F
    if (t == 0) {
        float S = sp[0][0] + sp[0][1] + sp[0][2] + sp[0][3];
        float Q = sp[1][0] + sp[1][1] + sp[1][2] + sp[1][3];
        float mean = S / (float)DD;
        float var = Q / (float)DD - mean * mean;
        stats[0] = mean;
        stats[1] = rsqrtf(var + 1e-5f);
    }
    __syncthreads();   // G
    const float mean = stats[0], inv = stats[1];
    const long base = (long)b * DD;
    float o0 = (v0 - mean) * inv * in_gamma[t] + in_beta[t];
    x0f[base + t] = o0; x0b[base + t] = f2b(o0);
    if (t < 136) {
        float o1 = (v1 - mean) * inv * in_gamma[256 + t] + in_beta[256 + t];
        x0f[base + 256 + t] = o1; x0b[base + 256 + t] = f2b(o1);
    }
}

// ---------------------------------------------------------------------------
// bf16 MFMA GEMM, 2-deep register prefetch + double-buffered LDS + XCD swizzle.
// out = f(A[M,K](bf16) @ WT[N,K]^T(bf16) + bias)
// MODE 0: +bias ; 1: relu(+bias) ; 2: cross: out = x0*(acc+bias)+xin
// 1-D grid, id m-major: id = mb*(NXB*NZB) + z*NXB + xb. grid%8 must be 0.
// ---------------------------------------------------------------------------
template<int MODE, int WF32, int WB16, int NXB, int NZB>
__global__ __launch_bounds__(256) void bgemm(
    const short* __restrict__ A, const short* __restrict__ WT,
    const float* __restrict__ bias,
    float* __restrict__ outF, short* __restrict__ outB,
    const float* __restrict__ x0, const float* __restrict__ xin,
    int M, int N, int K, long aZ, long wZ, long bZ, long oZ)
{
    __shared__ short As[2][64 * 64];   // swizzled: byte = r*128 + ((k*2)^((r&7)<<4))
    __shared__ short Bs[2][64 * 64];

    int id = blockIdx.x;
    const int qq = (int)gridDim.x >> 3;
    id = (id & 7) * qq + (id >> 3);
    const int mb  = id / (NXB * NZB);
    const int rem = id - mb * (NXB * NZB);
    const int z   = rem / NXB;
    const int xb  = rem - z * NXB;

    A += (long)z * aZ; WT += (long)z * wZ; bias += (long)z * bZ;
    const long oz = (long)z * oZ;

    const int t = threadIdx.x, w = t >> 6, lane = t & 63;
    const int m0 = mb * 64, n0 = xb * 64;
    const int sm = t >> 3, sk8 = (t & 7) << 3;

    f32x4 acc[4];
    #pragma unroll
    for (int i = 0; i < 4; ++i) {
        #pragma unroll
        for (int r = 0; r < 4; ++r) acc[i][r] = 0.f;
    }

    const int nsteps = (K + 63) >> 6;
    short8 avA[2], bvA[2], avB[2], bvB[2];

    auto loadA = [&](int k0) {
        #pragma unroll
        for (int i = 0; i < 2; ++i) {
            const int r = sm + (i << 5);
            short8 zv = {0, 0, 0, 0, 0, 0, 0, 0};
            avA[i] = zv; bvA[i] = zv;
            if (k0 + sk8 < K) {
                avA[i] = *reinterpret_cast<const short8*>(&A[(long)(m0 + r) * K + k0 + sk8]);
                if (n0 + r < N)
                    bvA[i] = *reinterpret_cast<const short8*>(&WT[(long)(n0 + r) * K + k0 + sk8]);
            }
        }
    };
    auto loadB = [&](int k0) {
        #pragma unroll
        for (int i = 0; i < 2; ++i) {
            const int r = sm + (i << 5);
            short8 zv = {0, 0, 0, 0, 0, 0, 0, 0};
            avB[i] = zv; bvB[i] = zv;
            if (k0 + sk8 < K) {
                avB[i] = *reinterpret_cast<const short8*>(&A[(long)(m0 + r) * K + k0 + sk8]);
                if (n0 + r < N)
                    bvB[i] = *reinterpret_cast<const short8*>(&WT[(long)(n0 + r) * K + k0 + sk8]);
            }
        }
    };
    auto wrA = [&](int buf) {
        #pragma unroll
        for (int i = 0; i < 2; ++i) {
            const int r = sm + (i << 5);
            const int byte = (r << 7) + ((sk8 << 1) ^ ((r & 7) << 4));
            *reinterpret_cast<short8*>(reinterpret_cast<char*>(&As[buf][0]) + byte) = avA[i];
            *reinterpret_cast<short8*>(reinterpret_cast<char*>(&Bs[buf][0]) + byte) = bvA[i];
        }
    };
    auto wrB = [&](int buf) {
        #pragma unroll
        for (int i = 0; i < 2; ++i) {
            const int r = sm + (i << 5);
            const int byte = (r << 7) + ((sk8 << 1) ^ ((r & 7) << 4));
            *reinterpret_cast<short8*>(reinterpret_cast<char*>(&As[buf][0]) + byte) = avB[i];
            *reinterpret_cast<short8*>(reinterpret_cast<char*>(&Bs[buf][0]) + byte) = bvB[i];
        }
    };
    auto domfma = [&](int buf) {
        #pragma unroll
        for (int kt = 0; kt < 2; ++kt) {
            const int kbyte = (kt << 6) + ((lane >> 4) << 4);
            const int ar = (w << 4) + (lane & 15);
            short8 a = *reinterpret_cast<const short8*>(
                reinterpret_cast<char*>(&As[buf][0]) + (ar << 7) + (kbyte ^ ((ar & 7) << 4)));
            #pragma unroll
            for (int nt = 0; nt < 4; ++nt) {
                const int br = (nt << 4) + (lane & 15);
                short8 bb = *reinterpret_cast<const short8*>(
                    reinterpret_cast<char*>(&Bs[buf][0]) + (br << 7) + (kbyte ^ ((br & 7) << 4)));
                acc[nt] = __builtin_amdgcn_mfma_f32_16x16x32_bf16(a, bb, acc[nt], 0, 0, 0);
            }
        }
    };

    // prologue: buf0 <- k0; regA <- k1; regB <- k2
    loadA(0);
    wrA(0);
    if (nsteps > 1) loadA(64);
    if (nsteps > 2) loadB(128);
    __syncthreads();

    int cur = 0, s = 0;
    while (s + 1 < nsteps) {
        domfma(cur);
        wrA(cur ^ 1);                       // regA holds k(s+1)
        if (s + 3 < nsteps) loadA((s + 3) << 6);
        __syncthreads(); cur ^= 1; ++s;
        if (s + 1 < nsteps) {
            domfma(cur);
            wrB(cur ^ 1);                   // regB holds k(s+1)
            if (s + 3 < nsteps) loadB((s + 3) << 6);
            __syncthreads(); cur ^= 1; ++s;
        }
    }
    domfma(cur);

    #pragma unroll
    for (int nt = 0; nt < 4; ++nt) {
        const int col = n0 + (nt << 4) + (lane & 15);
        if (col < N) {
            const float bv = bias[col];
            #pragma unroll
            for (int r = 0; r < 4; ++r) {
                const int row = m0 + (w << 4) + ((lane >> 4) << 2) + r;
                float v = acc[nt][r] + bv;
                if (MODE == 1) v = fmaxf(v, 0.f);
                const long o = (long)row * N + col;
                if (MODE == 2) v = x0[o] * v + xin[o];
                if (WF32) outF[oz + o] = v;
                if (WB16) outB[oz + o] = f2b(v);
            }
        }
    }
}

// ---------------------------------------------------------------------------
// LayerNorm over 392 (block per row), f32 + bf16 outputs
// ---------------------------------------------------------------------------
__global__ __launch_bounds__(256) void ln_kernel(
    const float* __restrict__ in,
    const float* __restrict__ gamma, const float* __restrict__ beta,
    float* __restrict__ outF, short* __restrict__ outB)
{
    __shared__ float red[2][4];
    __shared__ float stats[2];
    const int b = blockIdx.x, t = threadIdx.x, lane = t & 63, w = t >> 6;
    const long base = (long)b * DD;
    float v0 = in[base + t];
    float v1 = (t < 136) ? in[base + 256 + t] : 0.f;
    float s = v0 + v1, q2 = v0 * v0 + v1 * v1;
    #pragma unroll
    for (int off = 32; off > 0; off >>= 1) {
        s += __shfl_xor(s, off);
        q2 += __shfl_xor(q2, off);
    }
    if (lane == 0) { red[0][w] = s; red[1][w] = q2; }
    __syncthreads();
    if (t == 0) {
        float S = red[0][0] + red[0][1] + red[0][2] + red[0][3];
        float Q = red[1][0] + red[1][1] + red[1][2] + red[1][3];
        float mean = S / (float)DD;
        float var = Q / (float)DD - mean * mean;
        stats[0] = mean;
        stats[1] = rsqrtf(var + 1e-5f);
    }
    __syncthreads();
    const float mean = stats[0], inv = stats[1];
    float o0 = (v0 - mean) * inv * gamma[t] + beta[t];
    outF[base + t] = o0; outB[base + t] = f2b(o0);
    if (t < 136) {
        float o1 = (v1 - mean) * inv * gamma[256 + t] + beta[256 + t];
        outF[base + 256 + t] = o1; outB[base + 256 + t] = f2b(o1);
    }
}

// ---------------------------------------------------------------------------
// K3: gates (from x f32) + expert-head dots (from h1 bf16 via hw2) + mix.
// ---------------------------------------------------------------------------
__global__ __launch_bounds__(256) void final_kernel(
    const float* __restrict__ x, const short* __restrict__ h1,
    const float* __restrict__ hw2, const float* __restrict__ hc,
    const float* __restrict__ gate_w, const float* __restrict__ gate_b,
    const float* __restrict__ head_b, float* __restrict__ out)
{
    const int t = threadIdx.x, lane = t & 63, w = t >> 6;
    const int b = blockIdx.x * 4 + w;
    const float* xr = x + (long)b * DD;

    float xv[7];
    #pragma unroll
    for (int i = 0; i < 7; ++i) {
        int d = lane + (i << 6);
        xv[i] = (d < DD) ? xr[d] : 0.f;
    }

    float gl[8] = {0.f, 0.f, 0.f, 0.f, 0.f, 0.f, 0.f, 0.f};
    #pragma unroll
    for (int i = 0; i < 7; ++i) {
        int d = lane + (i << 6);
        if (d < DD) {
            float4 g0 = *reinterpret_cast<const float4*>(&gate_w[d << 2]);
            float4 g1 = *reinterpret_cast<const float4*>(&gate_w[1568 + (d << 2)]);
            gl[0] = fmaf(xv[i], g0.x, gl[0]); gl[1] = fmaf(xv[i], g0.y, gl[1]);
            gl[2] = fmaf(xv[i], g0.z, gl[2]); gl[3] = fmaf(xv[i], g0.w, gl[3]);
            gl[4] = fmaf(xv[i], g1.x, gl[4]); gl[5] = fmaf(xv[i], g1.y, gl[5]);
            gl[6] = fmaf(xv[i], g1.z, gl[6]); gl[7] = fmaf(xv[i], g1.w, gl[7]);
        }
    }

    float ed[8];
    #pragma unroll
    for (int e = 0; e < 4; ++e) {
        short4v hv = *reinterpret_cast<const short4v*>(
            &h1[((long)e * BB + b) * HH1 + (lane << 2)]);
        const float* hwp = &hw2[(((e << 8) + (lane << 2))) << 1];
        float4 w01 = *reinterpret_cast<const float4*>(hwp);
        float4 w23 = *reinterpret_cast<const float4*>(hwp + 4);
        float h0 = b2f(hv[0]), h1f = b2f(hv[1]), h2 = b2f(hv[2]), h3 = b2f(hv[3]);
        ed[e]     = fmaf(h0, w01.x, fmaf(h1f, w01.z, fmaf(h2, w23.x, h3 * w23.z)));
        ed[4 + e] = fmaf(h0, w01.y, fmaf(h1f, w01.w, fmaf(h2, w23.y, h3 * w23.w)));
    }

    #pragma unroll
    for (int v = 0; v < 8; ++v) {
        #pragma unroll
        for (int off = 32; off > 0; off >>= 1) {
            gl[v] += __shfl_xor(gl[v], off);
            ed[v] += __shfl_xor(ed[v], off);
        }
    }

    if (lane == 0) {
        float res[2];
        #pragma unroll
        for (int tt = 0; tt < 2; ++tt) {
            float lv[4], m = -1e30f;
            #pragma unroll
            for (int e = 0; e < 4; ++e) {
                lv[e] = gl[tt * 4 + e] + gate_b[tt * 4 + e];
                m = fmaxf(m, lv[e]);
            }
            float sum = 0.f, acc = 0.f;
            #pragma unroll
            for (int e = 0; e < 4; ++e) { lv[e] = __expf(lv[e] - m); sum += lv[e]; }
            #pragma unroll
            for (int e = 0; e < 4; ++e)
                acc = fmaf(lv[e], ed[tt * 4 + e] + hc[e * 2 + tt], acc);
            res[tt] = head_b[tt] + acc / sum;
        }
        out[b] = res[0];
        out[BB + b] = res[1];
    }
}

// ---------------------------------------------------------------------------
extern "C" void kernel_launch(void* const* d_in, const int* in_sizes, int n_in,
                              void* d_out, int out_size, void* d_ws, size_t ws_size,
                              hipStream_t stream) {
    const int*   userId    = (const int*)d_in[0];
    const int*   movieId   = (const int*)d_in[1];
    const int*   seq       = (const int*)d_in[2];
    const float* dense     = (const float*)d_in[3];
    const float* emb_user  = (const float*)d_in[4];
    const float* emb_movie = (const float*)d_in[5];
    const float* att_w1    = (const float*)d_in[6];
    const float* att_b1    = (const float*)d_in[7];
    const float* att_w2    = (const float*)d_in[8];
    const float* att_b2    = (const float*)d_in[9];
    const float* in_gamma  = (const float*)d_in[10];
    const float* in_beta   = (const float*)d_in[11];
    const float* cr_gamma  = (const float*)d_in[12];
    const float* cr_beta   = (const float*)d_in[13];
    const float* cross_W   = (const float*)d_in[14];
    const float* cross_b   = (const float*)d_in[15];
    const float* exp_w1    = (const float*)d_in[16];
    const float* exp_b1    = (const float*)d_in[17];
    const float* exp_w2    = (const float*)d_in[18];
    const float* exp_b2    = (const float*)d_in[19];
    const float* gate_w    = (const float*)d_in[20];
    const float* gate_b    = (const float*)d_in[21];
    const float* head_w    = (const float*)d_in[22];
    const float* head_b    = (const float*)d_in[23];
    float* outp = (float*)d_out;

    char* p = (char*)d_ws;
    auto alloc = [&](size_t bytes) -> char* {
        char* r = p; p += (bytes + 255) & ~(size_t)255; return r;
    };
    short* WqpT = (short*)alloc(8192 * 2);
    short* WkpF = (short*)alloc(16384 * 2);
    float* hw2 = (float*)alloc(2048 * 4);
    float* hc  = (float*)alloc(8 * 4);
    short* WTc = (short*)alloc((size_t)3 * 392 * 392 * 2);
    short* WT1 = (short*)alloc((size_t)4 * 256 * 392 * 2);
    short* embB = (short*)alloc((size_t)50001 * 128 * 2);
    float* x0f = (float*)alloc((size_t)BB * DD * 4);
    short* x0b = (short*)alloc((size_t)BB * DD * 2);
    float* xAf = (float*)alloc((size_t)BB * DD * 4);
    short* xAb = (short*)alloc((size_t)BB * DD * 2);
    float* xBf = (float*)alloc((size_t)BB * DD * 4);
    short* xBb = (short*)alloc((size_t)BB * DD * 2);
    short* h1b = (short*)alloc((size_t)4 * BB * HH1 * 2);

    prep_small<<<68, 256, 0, stream>>>(att_w1, exp_w2, exp_b2, head_w,
                                       WqpT, WkpF, hw2, hc);
    prep_trans<<<(S0 + S1 + S2 + 255) / 256, 256, 0, stream>>>(
        cross_W, exp_w1, emb_movie, WTc, WT1, embB);

    attn_kernel<<<BB, 256, 0, stream>>>(userId, movieId, seq, dense,
                                        emb_user, emb_movie, embB,
                                        WqpT, WkpF,
                                        att_b1, att_w2, att_b2,
                                        in_gamma, in_beta, x0f, x0b);

    // CrossNetV2: grid = 128 m-blocks * 7 n-blocks = 896 (%8==0)
    bgemm<2, 1, 1, 7, 1><<<896, 256, 0, stream>>>(x0b, WTc, cross_b, xAf, xAb,
                                                  x0f, x0f, BB, DD, DD, 0, 0, 0, 0);
    bgemm<2, 1, 1, 7, 1><<<896, 256, 0, stream>>>(xAb, WTc + 392 * 392, cross_b + 392,
                                                  xBf, xBb, x0f, xAf, BB, DD, DD, 0, 0, 0, 0);
    bgemm<2, 1, 0, 7, 1><<<896, 256, 0, stream>>>(xBb, WTc + 2 * 392 * 392, cross_b + 784,
                                                  xAf, nullptr, x0f, xBf, BB, DD, DD, 0, 0, 0, 0);

    // LN2: xAf -> xBf (+bf16)
    ln_kernel<<<BB, 256, 0, stream>>>(xAf, cr_gamma, cr_beta, xBf, xBb);

    // Experts layer 1: h1 = relu(x @ w1 + b1)  [E][B][256] bf16
    bgemm<1, 0, 1, 4, 4><<<2048, 256, 0, stream>>>(
        xBb, WT1, exp_b1, nullptr, h1b, nullptr, nullptr,
        BB, HH1, DD, 0, (long)HH1 * DD, HH1, (long)BB * HH1);

    // gates + expert-head dots + mix -> logits [2][B]
    final_kernel<<<BB / 4, 256, 0, stream>>>(xBf, h1b, hw2, hc,
                                             gate_w, gate_b, head_b, outp);

    (void)in_sizes; (void)n_in; (void)out_size; (void)ws_size;
}